// Round 1
// baseline (4849.441 us; speedup 1.0000x reference)
//
#include <hip/hip_runtime.h>
#include <stdint.h>

// ---------------- problem constants ----------------
#define TT 12
#define KK 50
#define VV 5000
#define BB 256
#define RHO_ 300
#define HT_ 800
#define HE_ 256
#define LOG_DELTA -5.2983174f   // log(0.005)
#define DENOM0 (1.0f + 1e-6f)
#define DENOM1 (0.005f + 1e-6f)

// JAX PRNG mode: 1 = threefry_partitionable (JAX >= 0.5 default), 0 = original
#define JAX_PARTITIONABLE 1

// ---------------- threefry2x32 (matches jax._src.prng) ----------------
__host__ __device__ inline void threefry2x32(uint32_t k0, uint32_t k1,
                                             uint32_t x0, uint32_t x1,
                                             uint32_t& o0, uint32_t& o1) {
  uint32_t ks2 = k0 ^ k1 ^ 0x1BD11BDAu;
  x0 += k0; x1 += k1;
#define TF_RND(r) { x0 += x1; x1 = (x1 << r) | (x1 >> (32 - r)); x1 ^= x0; }
  TF_RND(13) TF_RND(15) TF_RND(26) TF_RND(6)  x0 += k1;  x1 += ks2 + 1u;
  TF_RND(17) TF_RND(29) TF_RND(16) TF_RND(24) x0 += ks2; x1 += k0 + 2u;
  TF_RND(13) TF_RND(15) TF_RND(26) TF_RND(6)  x0 += k0;  x1 += k1 + 3u;
  TF_RND(17) TF_RND(29) TF_RND(16) TF_RND(24) x0 += k1;  x1 += ks2 + 4u;
  TF_RND(13) TF_RND(15) TF_RND(26) TF_RND(6)  x0 += ks2; x1 += k0 + 5u;
#undef TF_RND
  o0 = x0; o1 = x1;
}

// Giles single-precision erfinv (same approximation XLA uses for ErfInv f32)
__device__ inline float erfinv_f(float x) {
  float w = -log1pf(-x * x);
  float p;
  if (w < 5.0f) {
    w -= 2.5f;
    p = 2.81022636e-08f;
    p = fmaf(p, w, 3.43273939e-07f);
    p = fmaf(p, w, -3.5233877e-06f);
    p = fmaf(p, w, -4.39150654e-06f);
    p = fmaf(p, w, 0.00021858087f);
    p = fmaf(p, w, -0.00125372503f);
    p = fmaf(p, w, -0.00417768164f);
    p = fmaf(p, w, 0.246640727f);
    p = fmaf(p, w, 1.50140941f);
  } else {
    w = sqrtf(w) - 3.0f;
    p = -0.000200214257f;
    p = fmaf(p, w, 0.000100950558f);
    p = fmaf(p, w, 0.00134934322f);
    p = fmaf(p, w, -0.00367342844f);
    p = fmaf(p, w, 0.00573950773f);
    p = fmaf(p, w, -0.0076224613f);
    p = fmaf(p, w, 0.00943887047f);
    p = fmaf(p, w, 1.00167406f);
    p = fmaf(p, w, 2.83297682f);
  }
  return p * x;
}

// jax.random.normal element idx (flat, row-major), total n elements (n even)
__device__ inline float jax_normal_f(uint32_t k0, uint32_t k1, uint32_t idx, uint32_t half_n) {
  uint32_t o0, o1, bits;
#if JAX_PARTITIONABLE
  threefry2x32(k0, k1, 0u, idx, o0, o1);
  bits = o0 ^ o1;
#else
  uint32_t p = (idx < half_n) ? idx : idx - half_n;
  threefry2x32(k0, k1, p, p + half_n, o0, o1);
  bits = (idx < half_n) ? o0 : o1;
#endif
  float f = __uint_as_float((bits >> 9) | 0x3f800000u) - 1.0f;  // [0,1)
  const float lo = -0.99999994f;  // nextafter(-1,0) f32
  float u = fmaf(f, 2.0f, lo);    // (hi-lo) rounds to 2.0f in f32, as XLA computes
  u = fmaxf(lo, u);
  return 1.41421356f * erfinv_f(u);
}

__device__ inline float sigmoidf_(float x) { return 1.0f / (1.0f + expf(-x)); }

// block reduce (blockDim.x == 256) -> atomicAdd double
__device__ inline void blockReduceAtomicAdd(float v, double* target, float* redbuf) {
  int lane = threadIdx.x & 63, wid = threadIdx.x >> 6;
  #pragma unroll
  for (int off = 32; off; off >>= 1) v += __shfl_down(v, off, 64);
  if (lane == 0) redbuf[wid] = v;
  __syncthreads();
  if (threadIdx.x == 0) {
    float tot = redbuf[0] + redbuf[1] + redbuf[2] + redbuf[3];
    atomicAdd(target, (double)tot);
  }
}

// ---------------- kernels ----------------

// alphas[t,k,r] = mu_q_alpha[k,t,r] + eps * exp(0.5*ls[k,t,r])
__global__ void k_alphas(const float* __restrict__ mu_q, const float* __restrict__ ls_q,
                         float* __restrict__ alphas, uint32_t ka, uint32_t kb) {
  int i = blockIdx.x * 256 + threadIdx.x;
  if (i >= TT * KK * RHO_) return;
  int t = i / (KK * RHO_);
  int k = (i / RHO_) % KK;
  int r = i % RHO_;
  int src = k * (TT * RHO_) + t * RHO_ + r;
  float mu = mu_q[src], ls = ls_q[src];
  float eps = jax_normal_f(ka, kb, (uint32_t)i, (uint32_t)(TT * KK * RHO_ / 2));
  alphas[i] = mu + eps * expf(0.5f * ls);
}

__global__ void k_kld_alpha(const float* __restrict__ mu_q, const float* __restrict__ ls_q,
                            const float* __restrict__ alphas, double* __restrict__ acc) {
  __shared__ float red[4];
  int i = blockIdx.x * 256 + threadIdx.x;
  float kl = 0.f;
  if (i < TT * KK * RHO_) {
    int t = i / (KK * RHO_);
    int k = (i / RHO_) % KK;
    int r = i % RHO_;
    int src = k * (TT * RHO_) + t * RHO_ + r;
    float mu = mu_q[src];
    float qls = fminf(fmaxf(ls_q[src], -100.f), 100.f);
    float pmu = (t == 0) ? 0.f : alphas[(t - 1) * (KK * RHO_) + k * RHO_ + r];
    float pls = (t == 0) ? 0.f : LOG_DELTA;
    float denom = (t == 0) ? DENOM0 : DENOM1;
    float d = mu - pmu;
    kl = (expf(qls) + d * d) / denom - 1.0f + pls - qls;
  }
  blockReduceAtomicAdd(kl, &acc[2], red);
}

// C[M,N] = A[M,K] * B[N,K]^T (+bias) (+relu). 64x64 tile, 4x4 microtile.
__global__ __launch_bounds__(256) void gemm_tn(
    const float* __restrict__ A, const float* __restrict__ B, float* __restrict__ C,
    const float* __restrict__ bias, int M, int N, int K, int lda, int ldb, int ldc, int relu) {
  __shared__ float a_s[16][65];
  __shared__ float b_s[16][65];
  int tid = threadIdx.x;
  int tx = tid & 15, ty = tid >> 4;
  int n0 = blockIdx.x * 64, m0 = blockIdx.y * 64;
  float acc[4][4] = {};
  for (int k0 = 0; k0 < K; k0 += 16) {
    #pragma unroll
    for (int q = 0; q < 4; q++) {
      int idx = q * 256 + tid;
      int kl = idx & 15, ml = idx >> 4;
      int gm = m0 + ml, gk = k0 + kl;
      a_s[kl][ml] = (gm < M && gk < K) ? A[(size_t)gm * lda + gk] : 0.f;
      int gn = n0 + ml;
      b_s[kl][ml] = (gn < N && gk < K) ? B[(size_t)gn * ldb + gk] : 0.f;
    }
    __syncthreads();
    #pragma unroll
    for (int kk = 0; kk < 16; kk++) {
      float av[4], bv[4];
      #pragma unroll
      for (int i = 0; i < 4; i++) { av[i] = a_s[kk][ty * 4 + i]; bv[i] = b_s[kk][tx * 4 + i]; }
      #pragma unroll
      for (int i = 0; i < 4; i++)
        #pragma unroll
        for (int j = 0; j < 4; j++) acc[i][j] = fmaf(av[i], bv[j], acc[i][j]);
    }
    __syncthreads();
  }
  #pragma unroll
  for (int i = 0; i < 4; i++) {
    int m = m0 + ty * 4 + i;
    if (m >= M) continue;
    #pragma unroll
    for (int j = 0; j < 4; j++) {
      int n = n0 + tx * 4 + j;
      if (n >= N) continue;
      float c = acc[i][j] + (bias ? bias[n] : 0.f);
      if (relu) c = fmaxf(c, 0.f);
      C[(size_t)m * ldc + n] = c;
    }
  }
}

__global__ void k_softmax_rows(float* __restrict__ data, int ncols) {
  int row = blockIdx.x;
  float* d = data + (size_t)row * ncols;
  int tid = threadIdx.x;
  __shared__ float red[256];
  float m = -INFINITY;
  for (int v = tid; v < ncols; v += 256) m = fmaxf(m, d[v]);
  red[tid] = m; __syncthreads();
  for (int s = 128; s; s >>= 1) { if (tid < s) red[tid] = fmaxf(red[tid], red[tid + s]); __syncthreads(); }
  float mx = red[0]; __syncthreads();
  float sum = 0.f;
  for (int v = tid; v < ncols; v += 256) { float e = expf(d[v] - mx); d[v] = e; sum += e; }
  red[tid] = sum; __syncthreads();
  for (int s = 128; s; s >>= 1) { if (tid < s) red[tid] += red[tid + s]; __syncthreads(); }
  float inv = 1.0f / red[0];
  for (int v = tid; v < ncols; v += 256) d[v] *= inv;
}

__global__ void k_bias_combine(const float* a, const float* b, float* o) {
  int i = blockIdx.x * 256 + threadIdx.x;
  if (i < 4 * HE_) o[i] = a[i] + b[i];
}

__global__ void k_transpose_whh(const float* __restrict__ Whh, float* __restrict__ whhT) {
  int o = blockIdx.x * 256 + threadIdx.x;  // o = h*1024 + j
  if (o >= 4 * HE_ * HE_) return;
  int h = o >> 10, j = o & 1023;
  whhT[o] = Whh[(size_t)j * HE_ + h];
}

// one LSTM step; block handles 4 batch rows; grid = 64 blocks x 256 threads
__global__ __launch_bounds__(256) void k_lstm_step(
    const float* __restrict__ xg, const float* __restrict__ whhT,
    float* __restrict__ h_buf, float* __restrict__ c_buf,
    float* __restrict__ lstm_out, int t, int first) {
  __shared__ float hprev[4][256];
  __shared__ float g[4][1024];
  int tid = threadIdx.x;
  int b0 = blockIdx.x * 4;
  #pragma unroll
  for (int bb = 0; bb < 4; bb++)
    hprev[bb][tid] = first ? 0.f : h_buf[(size_t)(b0 + bb) * 256 + tid];
  __syncthreads();
  #pragma unroll
  for (int jj = 0; jj < 4; jj++) {
    int j = jj * 256 + tid;
    float a0 = 0, a1 = 0, a2 = 0, a3 = 0;
    for (int h = 0; h < 256; h++) {
      float w = whhT[(size_t)h * 1024 + j];
      a0 = fmaf(w, hprev[0][h], a0);
      a1 = fmaf(w, hprev[1][h], a1);
      a2 = fmaf(w, hprev[2][h], a2);
      a3 = fmaf(w, hprev[3][h], a3);
    }
    g[0][j] = xg[((size_t)(b0 + 0) * TT + t) * 1024 + j] + a0;
    g[1][j] = xg[((size_t)(b0 + 1) * TT + t) * 1024 + j] + a1;
    g[2][j] = xg[((size_t)(b0 + 2) * TT + t) * 1024 + j] + a2;
    g[3][j] = xg[((size_t)(b0 + 3) * TT + t) * 1024 + j] + a3;
  }
  __syncthreads();
  #pragma unroll
  for (int bb = 0; bb < 4; bb++) {
    int b = b0 + bb;
    float gi = g[bb][tid], gf = g[bb][256 + tid], gc = g[bb][512 + tid], go = g[bb][768 + tid];
    float c = first ? 0.f : c_buf[(size_t)b * 256 + tid];
    c = sigmoidf_(gf) * c + sigmoidf_(gi) * tanhf(gc);
    float h = sigmoidf_(go) * tanhf(c);
    c_buf[(size_t)b * 256 + tid] = c;
    h_buf[(size_t)b * 256 + tid] = h;
    lstm_out[((size_t)t * BB + b) * 256 + tid] = h;
  }
}

// one eta step; block per batch row b; 128 threads
__global__ __launch_bounds__(128) void k_eta_step(
    const float* __restrict__ lstm_out, const float* __restrict__ mue_W,
    const float* __restrict__ mue_b, const float* __restrict__ lse_W,
    const float* __restrict__ lse_b, float* __restrict__ etas,
    double* __restrict__ acc, int t, uint32_t ka, uint32_t kb) {
  int b = blockIdx.x, tid = threadIdx.x;
  __shared__ float z[HE_ + KK];
  __shared__ float mu_s[KK], ls_s[KK];
  for (int i = tid; i < HE_; i += 128) z[i] = lstm_out[((size_t)t * BB + b) * HE_ + i];
  for (int i = tid; i < KK; i += 128)
    z[HE_ + i] = (t == 0) ? 0.f : etas[((size_t)(t - 1) * BB + b) * KK + i];
  __syncthreads();
  if (tid < 100) {
    int j = tid % KK; bool isMu = tid < KK;
    const float* w = (isMu ? mue_W : lse_W) + (size_t)j * (HE_ + KK);
    float a = 0.f;
    for (int i = 0; i < HE_ + KK; i++) a = fmaf(z[i], w[i], a);
    a += (isMu ? mue_b : lse_b)[j];
    if (isMu) mu_s[j] = a; else ls_s[j] = a;
  }
  __syncthreads();
  if (tid < 64) {
    float kl = 0.f;
    if (tid < KK) {
      float mu = mu_s[tid], ls = ls_s[tid];
      float eps = jax_normal_f(ka, kb, (uint32_t)((t * BB + b) * KK + tid),
                               (uint32_t)(TT * BB * KK / 2));
      etas[((size_t)t * BB + b) * KK + tid] = mu + eps * expf(0.5f * ls);
      float qls = fminf(fmaxf(ls, -100.f), 100.f);
      float pmu = z[HE_ + tid];
      float pls = (t == 0) ? 0.f : LOG_DELTA;
      float denom = (t == 0) ? DENOM0 : DENOM1;
      float d = mu - pmu;
      kl = (expf(qls) + d * d) / denom - 1.0f + pls - qls;
    }
    #pragma unroll
    for (int off = 32; off; off >>= 1) kl += __shfl_down(kl, off, 64);
    if (tid == 0) atomicAdd(&acc[3], (double)kl);
  }
}

// h1[m, j] = relu(bows_part[b,j](incl qt_b1) + etas[m,:] . qt_W1[j, V: V+K])
__global__ __launch_bounds__(256) void k_h1(
    const float* __restrict__ etas, const float* __restrict__ qt_W1,
    const float* __restrict__ bows_part, float* __restrict__ h1) {
  int m = blockIdx.x;          // m = t*B + b
  int b = m & (BB - 1);
  int tid = threadIdx.x;
  __shared__ float el[KK];
  if (tid < KK) el[tid] = etas[(size_t)m * KK + tid];
  __syncthreads();
  for (int j = tid; j < HT_; j += 256) {
    const float* w = qt_W1 + (size_t)j * (VV + KK) + VV;
    float a = bows_part[(size_t)b * HT_ + j];
    #pragma unroll
    for (int k = 0; k < KK; k++) a = fmaf(el[k], w[k], a);
    h1[(size_t)m * HT_ + j] = fmaxf(a, 0.f);
  }
}

// theta: mu/ls from h2 row, sample z, softmax over K, kld_theta accumulation
__global__ __launch_bounds__(128) void k_theta(
    const float* __restrict__ h2, const float* __restrict__ mut_W,
    const float* __restrict__ mut_b, const float* __restrict__ lst_W,
    const float* __restrict__ lst_b, const float* __restrict__ etas,
    float* __restrict__ theta, double* __restrict__ acc, uint32_t ka, uint32_t kb) {
  int m = blockIdx.x;  // t*B + b
  int tid = threadIdx.x;
  __shared__ float hr[HT_];
  __shared__ float mu_s[KK], ls_s[KK];
  for (int i = tid; i < HT_; i += 128) hr[i] = h2[(size_t)m * HT_ + i];
  __syncthreads();
  if (tid < 100) {
    int j = tid % KK; bool isMu = tid < KK;
    const float* w = (isMu ? mut_W : lst_W) + (size_t)j * HT_;
    float a = 0.f;
    for (int i = 0; i < HT_; i++) a = fmaf(hr[i], w[i], a);
    a += (isMu ? mut_b : lst_b)[j];
    if (isMu) mu_s[j] = a; else ls_s[j] = a;
  }
  __syncthreads();
  if (tid < 64) {
    float kl = 0.f, zv = -INFINITY;
    if (tid < KK) {
      float mu = mu_s[tid], ls = ls_s[tid];
      float eps = jax_normal_f(ka, kb, (uint32_t)(m * KK + tid), (uint32_t)(TT * BB * KK / 2));
      zv = mu + eps * expf(0.5f * ls);
      float qls = fminf(fmaxf(ls, -100.f), 100.f);
      float e = etas[(size_t)m * KK + tid];
      float d = mu - e;
      kl = (expf(qls) + d * d) / DENOM0 - 1.0f - qls;
    }
    float mx = zv;
    #pragma unroll
    for (int off = 32; off; off >>= 1) mx = fmaxf(mx, __shfl_xor(mx, off, 64));
    float ev = (tid < KK) ? expf(zv - mx) : 0.f;
    float sum = ev;
    #pragma unroll
    for (int off = 32; off; off >>= 1) sum += __shfl_xor(sum, off, 64);
    if (tid < KK) theta[(size_t)m * KK + tid] = ev / sum;
    #pragma unroll
    for (int off = 32; off; off >>= 1) kl += __shfl_down(kl, off, 64);
    if (tid == 0) atomicAdd(&acc[1], (double)kl);
  }
}

// decode+nll: block = (bchunk of 8, t)
__global__ __launch_bounds__(256) void k_decode(
    const float* __restrict__ theta, const float* __restrict__ beta,
    const float* __restrict__ bow_t, double* __restrict__ acc) {
  __shared__ float red[4];
  __shared__ float th[8][KK];
  int t = blockIdx.y, b0 = blockIdx.x * 8, tid = threadIdx.x;
  for (int i = tid; i < 8 * KK; i += 256) {
    int bb = i / KK, k = i % KK;
    th[bb][k] = theta[((size_t)t * BB + b0 + bb) * KK + k];
  }
  __syncthreads();
  float s = 0.f;
  for (int v = tid; v < VV; v += 256) {
    float lik[8] = {0, 0, 0, 0, 0, 0, 0, 0};
    const float* bp = beta + (size_t)t * KK * VV + v;
    for (int k = 0; k < KK; k++) {
      float bv = bp[(size_t)k * VV];
      #pragma unroll
      for (int i = 0; i < 8; i++) lik[i] = fmaf(th[i][k], bv, lik[i]);
    }
    #pragma unroll
    for (int i = 0; i < 8; i++) {
      float bow = bow_t[((size_t)(b0 + i) * TT + t) * VV + v];
      s -= logf(lik[i] + 1e-6f) * bow;
    }
  }
  blockReduceAtomicAdd(s, &acc[0], red);
}

// cond: sum over (v,w) of A[v,w] * (M^T M)[v,w], M = beta [600, 5000]
__global__ __launch_bounds__(256) void k_cond(
    const float* __restrict__ beta, const float* __restrict__ adj, double* __restrict__ acc) {
  __shared__ float red[4];
  __shared__ float a_s[8][65];
  __shared__ float b_s[8][65];
  int tid = threadIdx.x;
  int tx = tid & 15, ty = tid >> 4;
  int w0 = blockIdx.x * 64, v0 = blockIdx.y * 64;
  float c[4][4] = {};
  for (int r0 = 0; r0 < TT * KK; r0 += 8) {
    #pragma unroll
    for (int q = 0; q < 2; q++) {
      int idx = q * 256 + tid;
      int rl = idx >> 6, vl = idx & 63;
      a_s[rl][vl] = (v0 + vl < VV) ? beta[(size_t)(r0 + rl) * VV + v0 + vl] : 0.f;
      b_s[rl][vl] = (w0 + vl < VV) ? beta[(size_t)(r0 + rl) * VV + w0 + vl] : 0.f;
    }
    __syncthreads();
    #pragma unroll
    for (int kk = 0; kk < 8; kk++) {
      float av[4], bv[4];
      #pragma unroll
      for (int i = 0; i < 4; i++) { av[i] = a_s[kk][ty * 4 + i]; bv[i] = b_s[kk][tx * 4 + i]; }
      #pragma unroll
      for (int i = 0; i < 4; i++)
        #pragma unroll
        for (int j = 0; j < 4; j++) c[i][j] = fmaf(av[i], bv[j], c[i][j]);
    }
    __syncthreads();
  }
  float s = 0.f;
  #pragma unroll
  for (int i = 0; i < 4; i++) {
    int v = v0 + ty * 4 + i;
    if (v >= VV) continue;
    #pragma unroll
    for (int j = 0; j < 4; j++) {
      int w = w0 + tx * 4 + j;
      if (w >= VV) continue;
      s += c[i][j] * adj[(size_t)v * VV + w];
    }
  }
  blockReduceAtomicAdd(s, &acc[4], red);
}

__global__ void k_final(const double* __restrict__ acc, float* __restrict__ out) {
  if (threadIdx.x == 0 && blockIdx.x == 0) {
    out[0] = (float)(acc[0] * (10.0 / (double)BB));                 // nll
    out[1] = (float)(acc[1] * (0.5 / ((double)TT * (double)BB)));   // kld_theta
    out[2] = (float)(acc[2] * (0.5 / ((double)TT * (double)KK)));   // kld_alpha
    out[3] = (float)(acc[3] * (0.5 / (double)BB));                  // kld_eta
    out[4] = (float)(acc[4] * (-0.01));                             // cond_loss
  }
}

// ---------------- host ----------------
extern "C" void kernel_launch(void* const* d_in, const int* in_sizes, int n_in,
                              void* d_out, int out_size, void* d_ws, size_t ws_size,
                              hipStream_t stream) {
  const float* normalized_bows = (const float*)d_in[0];
  const float* bow_t  = (const float*)d_in[1];
  const float* adj    = (const float*)d_in[2];
  const float* mu_q   = (const float*)d_in[3];
  const float* ls_q   = (const float*)d_in[4];
  const float* rho_W  = (const float*)d_in[5];
  const float* rho_b  = (const float*)d_in[6];
  const float* qt_W1  = (const float*)d_in[7];
  const float* qt_b1  = (const float*)d_in[8];
  const float* qt_W2  = (const float*)d_in[9];
  const float* qt_b2  = (const float*)d_in[10];
  const float* mut_W  = (const float*)d_in[11];
  const float* mut_b  = (const float*)d_in[12];
  const float* lst_W  = (const float*)d_in[13];
  const float* lst_b  = (const float*)d_in[14];
  const float* qe_W   = (const float*)d_in[15];
  const float* qe_b   = (const float*)d_in[16];
  const float* Wih    = (const float*)d_in[17];
  const float* Whh    = (const float*)d_in[18];
  const float* bih    = (const float*)d_in[19];
  const float* bhh    = (const float*)d_in[20];
  const float* mue_W  = (const float*)d_in[21];
  const float* mue_b  = (const float*)d_in[22];
  const float* lse_W  = (const float*)d_in[23];
  const float* lse_b  = (const float*)d_in[24];
  float* out = (float*)d_out;

  // workspace layout
  double* acc = (double*)d_ws;                    // 5 doubles (64B reserved)
  float* base = (float*)d_ws;
  float* alphas    = base + 16;                   // 180000
  float* beta      = alphas + 180000;             // 3,000,000
  float* inp       = beta + 3000000;              // 786,432   rows m = b*T+t
  float* xg        = inp + 786432;                // 3,145,728 rows m = b*T+t
  float* sumbias   = xg + 3145728;                // 1024
  float* whhT      = sumbias + 1024;              // 262,144
  float* h_buf     = whhT + 262144;               // 65,536
  float* c_buf     = h_buf + 65536;               // 65,536
  float* lstm_out  = c_buf + 65536;               // 786,432   [t][b][h]
  float* etas      = lstm_out + 786432;           // 153,600   [t][b][k]
  float* bows_part = etas + 153600;               // 204,800   [b][j]
  float* h1        = bows_part + 204800;          // 2,457,600 rows m = t*B+b
  float* h2        = h1 + 2457600;                // 2,457,600
  float* theta     = h2 + 2457600;                // 153,600

  // derive JAX keys: key(42) -> split(3)
  uint32_t e0a, e0b, e1a, e1b, e2a, e2b;
#if JAX_PARTITIONABLE
  threefry2x32(0u, 42u, 0u, 0u, e0a, e0b);
  threefry2x32(0u, 42u, 0u, 1u, e1a, e1b);
  threefry2x32(0u, 42u, 0u, 2u, e2a, e2b);
#else
  uint32_t r00, r01, r10, r11, r20, r21;
  threefry2x32(0u, 42u, 0u, 3u, r00, r01);
  threefry2x32(0u, 42u, 1u, 4u, r10, r11);
  threefry2x32(0u, 42u, 2u, 5u, r20, r21);
  e0a = r00; e0b = r10;
  e1a = r20; e1b = r01;
  e2a = r11; e2b = r21;
#endif

  hipMemsetAsync(acc, 0, 5 * sizeof(double), stream);

  // alphas + kld_alpha
  k_alphas<<<704, 256, 0, stream>>>(mu_q, ls_q, alphas, e0a, e0b);
  k_kld_alpha<<<704, 256, 0, stream>>>(mu_q, ls_q, alphas, acc);

  // beta = softmax(alphas @ rho_W^T + rho_b)
  gemm_tn<<<dim3(79, 10), 256, 0, stream>>>(alphas, rho_W, beta, rho_b,
                                            600, VV, RHO_, RHO_, RHO_, VV, 0);
  k_softmax_rows<<<600, 256, 0, stream>>>(beta, VV);

  // LSTM input: inp = bow_t @ qe_W^T + qe_b   (rows m = b*T+t)
  gemm_tn<<<dim3(4, 48), 256, 0, stream>>>(bow_t, qe_W, inp, qe_b,
                                           BB * TT, HE_, VV, VV, VV, HE_, 0);
  // xg = inp @ Wih^T + (bih + bhh)
  k_bias_combine<<<4, 256, 0, stream>>>(bih, bhh, sumbias);
  gemm_tn<<<dim3(16, 48), 256, 0, stream>>>(inp, Wih, xg, sumbias,
                                            BB * TT, 4 * HE_, HE_, HE_, HE_, 4 * HE_, 0);
  k_transpose_whh<<<1024, 256, 0, stream>>>(Whh, whhT);

  for (int t = 0; t < TT; t++)
    k_lstm_step<<<64, 256, 0, stream>>>(xg, whhT, h_buf, c_buf, lstm_out, t, t == 0);

  for (int t = 0; t < TT; t++)
    k_eta_step<<<BB, 128, 0, stream>>>(lstm_out, mue_W, mue_b, lse_W, lse_b,
                                       etas, acc, t, e1a, e1b);

  // theta encoder: bows part (T-invariant) then per-(t,b) eta part
  gemm_tn<<<dim3(13, 4), 256, 0, stream>>>(normalized_bows, qt_W1, bows_part, qt_b1,
                                           BB, HT_, VV, VV, VV + KK, HT_, 0);
  k_h1<<<TT * BB, 256, 0, stream>>>(etas, qt_W1, bows_part, h1);
  gemm_tn<<<dim3(13, 48), 256, 0, stream>>>(h1, qt_W2, h2, qt_b2,
                                            TT * BB, HT_, HT_, HT_, HT_, HT_, 1);
  k_theta<<<TT * BB, 128, 0, stream>>>(h2, mut_W, mut_b, lst_W, lst_b, etas,
                                       theta, acc, e2a, e2b);

  // decode + nll
  k_decode<<<dim3(32, 12), 256, 0, stream>>>(theta, beta, bow_t, acc);

  // adjacency quadratic form
  k_cond<<<dim3(79, 79), 256, 0, stream>>>(beta, adj, acc);

  k_final<<<1, 64, 0, stream>>>(acc, out);
}

// Round 2
// 1524.024 us; speedup vs baseline: 3.1820x; 3.1820x over previous
//
#include <hip/hip_runtime.h>
#include <stdint.h>

// ---------------- problem constants ----------------
#define TT 12
#define KK 50
#define VV 5000
#define BB 256
#define RHO_ 300
#define HT_ 800
#define HE_ 256
#define LOG_DELTA -5.2983174f   // log(0.005)
#define DENOM0 (1.0f + 1e-6f)
#define DENOM1 (0.005f + 1e-6f)

#define JAX_PARTITIONABLE 1

typedef __attribute__((ext_vector_type(8))) short short8;
typedef __attribute__((ext_vector_type(4))) float f32x4;

// ---------------- threefry2x32 (matches jax._src.prng) ----------------
__host__ __device__ inline void threefry2x32(uint32_t k0, uint32_t k1,
                                             uint32_t x0, uint32_t x1,
                                             uint32_t& o0, uint32_t& o1) {
  uint32_t ks2 = k0 ^ k1 ^ 0x1BD11BDAu;
  x0 += k0; x1 += k1;
#define TF_RND(r) { x0 += x1; x1 = (x1 << r) | (x1 >> (32 - r)); x1 ^= x0; }
  TF_RND(13) TF_RND(15) TF_RND(26) TF_RND(6)  x0 += k1;  x1 += ks2 + 1u;
  TF_RND(17) TF_RND(29) TF_RND(16) TF_RND(24) x0 += ks2; x1 += k0 + 2u;
  TF_RND(13) TF_RND(15) TF_RND(26) TF_RND(6)  x0 += k0;  x1 += k1 + 3u;
  TF_RND(17) TF_RND(29) TF_RND(16) TF_RND(24) x0 += k1;  x1 += ks2 + 4u;
  TF_RND(13) TF_RND(15) TF_RND(26) TF_RND(6)  x0 += ks2; x1 += k0 + 5u;
#undef TF_RND
  o0 = x0; o1 = x1;
}

__device__ inline float erfinv_f(float x) {
  float w = -log1pf(-x * x);
  float p;
  if (w < 5.0f) {
    w -= 2.5f;
    p = 2.81022636e-08f;
    p = fmaf(p, w, 3.43273939e-07f);
    p = fmaf(p, w, -3.5233877e-06f);
    p = fmaf(p, w, -4.39150654e-06f);
    p = fmaf(p, w, 0.00021858087f);
    p = fmaf(p, w, -0.00125372503f);
    p = fmaf(p, w, -0.00417768164f);
    p = fmaf(p, w, 0.246640727f);
    p = fmaf(p, w, 1.50140941f);
  } else {
    w = sqrtf(w) - 3.0f;
    p = -0.000200214257f;
    p = fmaf(p, w, 0.000100950558f);
    p = fmaf(p, w, 0.00134934322f);
    p = fmaf(p, w, -0.00367342844f);
    p = fmaf(p, w, 0.00573950773f);
    p = fmaf(p, w, -0.0076224613f);
    p = fmaf(p, w, 0.00943887047f);
    p = fmaf(p, w, 1.00167406f);
    p = fmaf(p, w, 2.83297682f);
  }
  return p * x;
}

__device__ inline float jax_normal_f(uint32_t k0, uint32_t k1, uint32_t idx, uint32_t half_n) {
  uint32_t o0, o1, bits;
#if JAX_PARTITIONABLE
  threefry2x32(k0, k1, 0u, idx, o0, o1);
  bits = o0 ^ o1;
#else
  uint32_t p = (idx < half_n) ? idx : idx - half_n;
  threefry2x32(k0, k1, p, p + half_n, o0, o1);
  bits = (idx < half_n) ? o0 : o1;
#endif
  float f = __uint_as_float((bits >> 9) | 0x3f800000u) - 1.0f;
  const float lo = -0.99999994f;
  float u = fmaf(f, 2.0f, lo);
  u = fmaxf(lo, u);
  return 1.41421356f * erfinv_f(u);
}

__device__ inline float sigmoidf_(float x) { return 1.0f / (1.0f + expf(-x)); }

// float -> bf16 bits (RNE)
__device__ inline short f2bf(float f) {
  uint32_t x = __float_as_uint(f);
  uint32_t r = (x + 0x7fffu + ((x >> 16) & 1u)) >> 16;
  return (short)r;
}

__device__ inline void blockReduceAtomicAdd(float v, double* target, float* redbuf) {
  int lane = threadIdx.x & 63, wid = threadIdx.x >> 6;
  #pragma unroll
  for (int off = 32; off; off >>= 1) v += __shfl_down(v, off, 64);
  if (lane == 0) redbuf[wid] = v;
  __syncthreads();
  if (threadIdx.x == 0) {
    float tot = redbuf[0] + redbuf[1] + redbuf[2] + redbuf[3];
    atomicAdd(target, (double)tot);
  }
}

// ---------------- MFMA GEMM: C[M,N] = A[M,K] * B[N,K]^T ----------------
// MODE 0: store C (+bias,+relu)   MODE 1: split-K atomicAdd into pre-init C
// MODE 2: s = sum(D * aux[m*N+n]) -> atomicAdd slot   (cond)
// MODE 3: s = -sum(log(D+1e-6)*aux[(m*TT+z)*VV+n]) -> slot  (decode; A/B offset by z)
// AF32: A source is fp32 (converted to bf16 during staging). B is always bf16.
template<int MODE, int AF32>
__global__ __launch_bounds__(256) void mfma_gemm(
    const void* __restrict__ Ap, const short* __restrict__ Bp,
    float* __restrict__ C, const float* __restrict__ bias,
    const float* __restrict__ aux, double* __restrict__ slot,
    int M, int N, int K, int lda, int ldb, int ldc,
    int kchunk, int relu)
{
  __shared__ alignas(16) short As[128 * 40];
  __shared__ alignas(16) short Bs[128 * 40];
  __shared__ float redg[4];
  int tid = threadIdx.x, lane = tid & 63, wv = tid >> 6;
  int wm = wv >> 1, wn = wv & 1;
  int quad = lane >> 4, l16 = lane & 15;
  int m0 = blockIdx.y * 128, n0 = blockIdx.x * 128;
  int z = blockIdx.z;
  int kbeg = (MODE == 1) ? z * kchunk : 0;
  int kend = (MODE == 1) ? min(K, kbeg + kchunk) : K;
  size_t aoff = (MODE == 3) ? (size_t)z * (size_t)M * (size_t)lda : 0;
  int boff = (MODE == 3) ? z * K : 0;
  const short* Ab = (const short*)Ap;
  const float* Af = (const float*)Ap;

  f32x4 acc[16];
  #pragma unroll
  for (int i = 0; i < 16; i++) acc[i] = (f32x4){0.f, 0.f, 0.f, 0.f};

  int srow = tid >> 2, skc = (tid & 3) * 8;
  for (int k0 = kbeg; k0 < kend; k0 += 32) {
    #pragma unroll
    for (int p = 0; p < 2; p++) {
      int row = srow + p * 64;
      int gk = k0 + skc;
      int rem = kend - gk;
      // ---- A tile ----
      short8 av = {0, 0, 0, 0, 0, 0, 0, 0};
      int gm = m0 + row;
      if (gm < M && rem > 0) {
        if (AF32) {
          const float* s = Af + aoff + (size_t)gm * lda + gk;
          if (rem >= 8) {
            float4 f0 = *(const float4*)(s);
            float4 f1 = *(const float4*)(s + 4);
            av[0] = f2bf(f0.x); av[1] = f2bf(f0.y); av[2] = f2bf(f0.z); av[3] = f2bf(f0.w);
            av[4] = f2bf(f1.x); av[5] = f2bf(f1.y); av[6] = f2bf(f1.z); av[7] = f2bf(f1.w);
          } else {
            for (int e = 0; e < 8; e++) if (e < rem) av[e] = f2bf(s[e]);
          }
        } else {
          const short* s = Ab + aoff + (size_t)gm * lda + gk;
          if (rem >= 8) {
            const uint32_t* u = (const uint32_t*)s;
            uint32_t u0 = u[0], u1 = u[1], u2 = u[2], u3 = u[3];
            av[0] = (short)u0; av[1] = (short)(u0 >> 16);
            av[2] = (short)u1; av[3] = (short)(u1 >> 16);
            av[4] = (short)u2; av[5] = (short)(u2 >> 16);
            av[6] = (short)u3; av[7] = (short)(u3 >> 16);
          } else {
            for (int e = 0; e < 8; e++) if (e < rem) av[e] = s[e];
          }
        }
      }
      *(short8*)(&As[row * 40 + skc]) = av;
      // ---- B tile ----
      short8 bv = {0, 0, 0, 0, 0, 0, 0, 0};
      int gn = n0 + row;
      if (gn < N && rem > 0) {
        const short* s = Bp + (size_t)gn * ldb + boff + gk;
        if (rem >= 8) {
          const uint32_t* u = (const uint32_t*)s;
          uint32_t u0 = u[0], u1 = u[1], u2 = u[2], u3 = u[3];
          bv[0] = (short)u0; bv[1] = (short)(u0 >> 16);
          bv[2] = (short)u1; bv[3] = (short)(u1 >> 16);
          bv[4] = (short)u2; bv[5] = (short)(u2 >> 16);
          bv[6] = (short)u3; bv[7] = (short)(u3 >> 16);
        } else {
          for (int e = 0; e < 8; e++) if (e < rem) bv[e] = s[e];
        }
      }
      *(short8*)(&Bs[row * 40 + skc]) = bv;
    }
    __syncthreads();
    short8 af[4], bfr[4];
    const short* ap = &As[(wm * 64 + l16) * 40 + quad * 8];
    const short* bp = &Bs[(wn * 64 + l16) * 40 + quad * 8];
    #pragma unroll
    for (int i = 0; i < 4; i++) af[i] = *(const short8*)(ap + i * 16 * 40);
    #pragma unroll
    for (int j = 0; j < 4; j++) bfr[j] = *(const short8*)(bp + j * 16 * 40);
    #pragma unroll
    for (int i = 0; i < 4; i++)
      #pragma unroll
      for (int j = 0; j < 4; j++)
        acc[i * 4 + j] = __builtin_amdgcn_mfma_f32_16x16x32_bf16(af[i], bfr[j], acc[i * 4 + j], 0, 0, 0);
    __syncthreads();
  }

  // ---- epilogue ----
  float s = 0.f;
  #pragma unroll
  for (int i = 0; i < 4; i++) {
    int gmb = m0 + wm * 64 + i * 16 + quad * 4;
    #pragma unroll
    for (int j = 0; j < 4; j++) {
      int gn = n0 + wn * 64 + j * 16 + l16;
      f32x4 v = acc[i * 4 + j];
      if (gn >= N) continue;
      if (MODE == 0) {
        float bs = bias ? bias[gn] : 0.f;
        #pragma unroll
        for (int r = 0; r < 4; r++) {
          int gm = gmb + r;
          if (gm < M) {
            float c = v[r] + bs;
            if (relu) c = fmaxf(c, 0.f);
            C[(size_t)gm * ldc + gn] = c;
          }
        }
      } else if (MODE == 1) {
        #pragma unroll
        for (int r = 0; r < 4; r++) {
          int gm = gmb + r;
          if (gm < M) atomicAdd(&C[(size_t)gm * ldc + gn], v[r]);
        }
      } else if (MODE == 2) {
        #pragma unroll
        for (int r = 0; r < 4; r++) {
          int gm = gmb + r;
          if (gm < M) s += v[r] * aux[(size_t)gm * N + gn];
        }
      } else {
        #pragma unroll
        for (int r = 0; r < 4; r++) {
          int gm = gmb + r;
          if (gm < M) s -= logf(v[r] + 1e-6f) * aux[((size_t)gm * TT + z) * VV + gn];
        }
      }
    }
  }
  if (MODE >= 2) {
    #pragma unroll
    for (int off = 32; off; off >>= 1) s += __shfl_down(s, off, 64);
    if (lane == 0) redg[wv] = s;
    __syncthreads();
    if (tid == 0) atomicAdd(slot, (double)(redg[0] + redg[1] + redg[2] + redg[3]));
  }
}

// ---------------- small kernels ----------------

__global__ void k_cvt(const float* __restrict__ in, short* __restrict__ out, int n) {
  int i = blockIdx.x * 256 + threadIdx.x;
  if (i < n) out[i] = f2bf(in[i]);
}

__global__ void k_cvt2d(const float* __restrict__ in, short* __restrict__ out,
                        int rows, int cols, int ldi, int ldo) {
  int i = blockIdx.x * 256 + threadIdx.x;
  if (i >= rows * cols) return;
  int r = i / cols, c = i % cols;
  out[(size_t)r * ldo + c] = f2bf(in[(size_t)r * ldi + c]);
}

__global__ void k_initbias(float* __restrict__ C, const float* __restrict__ bias,
                           int nmod, int total) {
  int i = blockIdx.x * 256 + threadIdx.x;
  if (i < total) C[i] = bias[i % nmod];
}

__global__ void k_alphas(const float* __restrict__ mu_q, const float* __restrict__ ls_q,
                         float* __restrict__ alphas, short* __restrict__ alph_bf,
                         uint32_t ka, uint32_t kb) {
  int i = blockIdx.x * 256 + threadIdx.x;
  if (i >= TT * KK * RHO_) return;
  int t = i / (KK * RHO_);
  int k = (i / RHO_) % KK;
  int r = i % RHO_;
  int src = k * (TT * RHO_) + t * RHO_ + r;
  float mu = mu_q[src], ls = ls_q[src];
  float eps = jax_normal_f(ka, kb, (uint32_t)i, (uint32_t)(TT * KK * RHO_ / 2));
  float a = mu + eps * expf(0.5f * ls);
  alphas[i] = a;
  int row = i / RHO_;                 // t*KK + k
  alph_bf[(size_t)row * 304 + r] = f2bf(a);
}

__global__ void k_kld_alpha(const float* __restrict__ mu_q, const float* __restrict__ ls_q,
                            const float* __restrict__ alphas, double* __restrict__ acc) {
  __shared__ float red[4];
  int i = blockIdx.x * 256 + threadIdx.x;
  float kl = 0.f;
  if (i < TT * KK * RHO_) {
    int t = i / (KK * RHO_);
    int k = (i / RHO_) % KK;
    int r = i % RHO_;
    int src = k * (TT * RHO_) + t * RHO_ + r;
    float mu = mu_q[src];
    float qls = fminf(fmaxf(ls_q[src], -100.f), 100.f);
    float pmu = (t == 0) ? 0.f : alphas[(t - 1) * (KK * RHO_) + k * RHO_ + r];
    float pls = (t == 0) ? 0.f : LOG_DELTA;
    float denom = (t == 0) ? DENOM0 : DENOM1;
    float d = mu - pmu;
    kl = (expf(qls) + d * d) / denom - 1.0f + pls - qls;
  }
  blockReduceAtomicAdd(kl, &acc[2], red);
}

__global__ void k_softmax_bf(const float* __restrict__ in, short* __restrict__ out, int ncols) {
  int row = blockIdx.x;
  const float* d = in + (size_t)row * ncols;
  short* o = out + (size_t)row * ncols;
  int tid = threadIdx.x;
  __shared__ float red[256];
  float m = -INFINITY;
  for (int v = tid; v < ncols; v += 256) m = fmaxf(m, d[v]);
  red[tid] = m; __syncthreads();
  for (int s = 128; s; s >>= 1) { if (tid < s) red[tid] = fmaxf(red[tid], red[tid + s]); __syncthreads(); }
  float mx = red[0]; __syncthreads();
  float sum = 0.f;
  for (int v = tid; v < ncols; v += 256) sum += expf(d[v] - mx);
  red[tid] = sum; __syncthreads();
  for (int s = 128; s; s >>= 1) { if (tid < s) red[tid] += red[tid + s]; __syncthreads(); }
  float inv = 1.0f / red[0];
  for (int v = tid; v < ncols; v += 256) o[v] = f2bf(expf(d[v] - mx) * inv);
}

// in[R][C] -> out[C][R]  (bf16)
__global__ __launch_bounds__(256) void k_transpose_bf(const short* __restrict__ in,
                                                      short* __restrict__ out, int R, int Cc) {
  __shared__ short tile[32][33];
  int c0 = blockIdx.x * 32, r0 = blockIdx.y * 32;
  int tx = threadIdx.x & 31, ty = threadIdx.x >> 5;  // 8 rows of 32
  for (int rr = ty; rr < 32; rr += 8) {
    int r = r0 + rr, c = c0 + tx;
    tile[rr][tx] = (r < R && c < Cc) ? in[(size_t)r * Cc + c] : (short)0;
  }
  __syncthreads();
  for (int cc = ty; cc < 32; cc += 8) {
    int c = c0 + cc, r = r0 + tx;
    if (c < Cc && r < R) out[(size_t)c * R + r] = tile[tx][cc];
  }
}

__global__ void k_bias_combine(const float* a, const float* b, float* o) {
  int i = blockIdx.x * 256 + threadIdx.x;
  if (i < 4 * HE_) o[i] = a[i] + b[i];
}

__global__ void k_transpose_whh(const float* __restrict__ Whh, float* __restrict__ whhT) {
  int o = blockIdx.x * 256 + threadIdx.x;
  if (o >= 4 * HE_ * HE_) return;
  int h = o >> 10, j = o & 1023;
  whhT[o] = Whh[(size_t)j * HE_ + h];
}

__global__ __launch_bounds__(256) void k_lstm_step(
    const float* __restrict__ xg, const float* __restrict__ whhT,
    float* __restrict__ h_buf, float* __restrict__ c_buf,
    float* __restrict__ lstm_out, int t, int first) {
  __shared__ float hprev[4][256];
  __shared__ float g[4][1024];
  int tid = threadIdx.x;
  int b0 = blockIdx.x * 4;
  #pragma unroll
  for (int bb = 0; bb < 4; bb++)
    hprev[bb][tid] = first ? 0.f : h_buf[(size_t)(b0 + bb) * 256 + tid];
  __syncthreads();
  #pragma unroll
  for (int jj = 0; jj < 4; jj++) {
    int j = jj * 256 + tid;
    float a0 = 0, a1 = 0, a2 = 0, a3 = 0;
    for (int h = 0; h < 256; h++) {
      float w = whhT[(size_t)h * 1024 + j];
      a0 = fmaf(w, hprev[0][h], a0);
      a1 = fmaf(w, hprev[1][h], a1);
      a2 = fmaf(w, hprev[2][h], a2);
      a3 = fmaf(w, hprev[3][h], a3);
    }
    g[0][j] = xg[((size_t)(b0 + 0) * TT + t) * 1024 + j] + a0;
    g[1][j] = xg[((size_t)(b0 + 1) * TT + t) * 1024 + j] + a1;
    g[2][j] = xg[((size_t)(b0 + 2) * TT + t) * 1024 + j] + a2;
    g[3][j] = xg[((size_t)(b0 + 3) * TT + t) * 1024 + j] + a3;
  }
  __syncthreads();
  #pragma unroll
  for (int bb = 0; bb < 4; bb++) {
    int b = b0 + bb;
    float gi = g[bb][tid], gf = g[bb][256 + tid], gc = g[bb][512 + tid], go = g[bb][768 + tid];
    float c = first ? 0.f : c_buf[(size_t)b * 256 + tid];
    c = sigmoidf_(gf) * c + sigmoidf_(gi) * tanhf(gc);
    float h = sigmoidf_(go) * tanhf(c);
    c_buf[(size_t)b * 256 + tid] = c;
    h_buf[(size_t)b * 256 + tid] = h;
    lstm_out[((size_t)t * BB + b) * 256 + tid] = h;
  }
}

__global__ __launch_bounds__(128) void k_eta_step(
    const float* __restrict__ lstm_out, const float* __restrict__ mue_W,
    const float* __restrict__ mue_b, const float* __restrict__ lse_W,
    const float* __restrict__ lse_b, float* __restrict__ etas,
    double* __restrict__ acc, int t, uint32_t ka, uint32_t kb) {
  int b = blockIdx.x, tid = threadIdx.x;
  __shared__ float z[HE_ + KK];
  __shared__ float mu_s[KK], ls_s[KK];
  for (int i = tid; i < HE_; i += 128) z[i] = lstm_out[((size_t)t * BB + b) * HE_ + i];
  for (int i = tid; i < KK; i += 128)
    z[HE_ + i] = (t == 0) ? 0.f : etas[((size_t)(t - 1) * BB + b) * KK + i];
  __syncthreads();
  if (tid < 100) {
    int j = tid % KK; bool isMu = tid < KK;
    const float* w = (isMu ? mue_W : lse_W) + (size_t)j * (HE_ + KK);
    float a = 0.f;
    for (int i = 0; i < HE_ + KK; i++) a = fmaf(z[i], w[i], a);
    a += (isMu ? mue_b : lse_b)[j];
    if (isMu) mu_s[j] = a; else ls_s[j] = a;
  }
  __syncthreads();
  if (tid < 64) {
    float kl = 0.f;
    if (tid < KK) {
      float mu = mu_s[tid], ls = ls_s[tid];
      float eps = jax_normal_f(ka, kb, (uint32_t)((t * BB + b) * KK + tid),
                               (uint32_t)(TT * BB * KK / 2));
      etas[((size_t)t * BB + b) * KK + tid] = mu + eps * expf(0.5f * ls);
      float qls = fminf(fmaxf(ls, -100.f), 100.f);
      float pmu = z[HE_ + tid];
      float pls = (t == 0) ? 0.f : LOG_DELTA;
      float denom = (t == 0) ? DENOM0 : DENOM1;
      float d = mu - pmu;
      kl = (expf(qls) + d * d) / denom - 1.0f + pls - qls;
    }
    #pragma unroll
    for (int off = 32; off; off >>= 1) kl += __shfl_down(kl, off, 64);
    if (tid == 0) atomicAdd(&acc[3], (double)kl);
  }
}

__global__ __launch_bounds__(256) void k_h1(
    const float* __restrict__ etas, const float* __restrict__ qt_W1,
    const float* __restrict__ bows_part, short* __restrict__ h1_bf) {
  int m = blockIdx.x;
  int b = m & (BB - 1);
  int tid = threadIdx.x;
  __shared__ float el[KK];
  if (tid < KK) el[tid] = etas[(size_t)m * KK + tid];
  __syncthreads();
  for (int j = tid; j < HT_; j += 256) {
    const float* w = qt_W1 + (size_t)j * (VV + KK) + VV;
    float a = bows_part[(size_t)b * HT_ + j];
    #pragma unroll
    for (int k = 0; k < KK; k++) a = fmaf(el[k], w[k], a);
    h1_bf[(size_t)m * HT_ + j] = f2bf(fmaxf(a, 0.f));
  }
}

__global__ __launch_bounds__(128) void k_theta(
    const float* __restrict__ h2, const float* __restrict__ mut_W,
    const float* __restrict__ mut_b, const float* __restrict__ lst_W,
    const float* __restrict__ lst_b, const float* __restrict__ etas,
    short* __restrict__ theta_bf, double* __restrict__ acc, uint32_t ka, uint32_t kb) {
  int m = blockIdx.x;
  int tid = threadIdx.x;
  __shared__ float hr[HT_];
  __shared__ float mu_s[KK], ls_s[KK];
  for (int i = tid; i < HT_; i += 128) hr[i] = h2[(size_t)m * HT_ + i];
  __syncthreads();
  if (tid < 100) {
    int j = tid % KK; bool isMu = tid < KK;
    const float* w = (isMu ? mut_W : lst_W) + (size_t)j * HT_;
    float a = 0.f;
    for (int i = 0; i < HT_; i++) a = fmaf(hr[i], w[i], a);
    a += (isMu ? mut_b : lst_b)[j];
    if (isMu) mu_s[j] = a; else ls_s[j] = a;
  }
  __syncthreads();
  if (tid < 64) {
    float kl = 0.f, zv = -INFINITY;
    if (tid < KK) {
      float mu = mu_s[tid], ls = ls_s[tid];
      float eps = jax_normal_f(ka, kb, (uint32_t)(m * KK + tid), (uint32_t)(TT * BB * KK / 2));
      zv = mu + eps * expf(0.5f * ls);
      float qls = fminf(fmaxf(ls, -100.f), 100.f);
      float e = etas[(size_t)m * KK + tid];
      float d = mu - e;
      kl = (expf(qls) + d * d) / DENOM0 - 1.0f - qls;
    }
    float mx = zv;
    #pragma unroll
    for (int off = 32; off; off >>= 1) mx = fmaxf(mx, __shfl_xor(mx, off, 64));
    float ev = (tid < KK) ? expf(zv - mx) : 0.f;
    float sum = ev;
    #pragma unroll
    for (int off = 32; off; off >>= 1) sum += __shfl_xor(sum, off, 64);
    if (tid < KK) theta_bf[(size_t)m * 56 + tid] = f2bf(ev / sum);
    #pragma unroll
    for (int off = 32; off; off >>= 1) kl += __shfl_down(kl, off, 64);
    if (tid == 0) atomicAdd(&acc[1], (double)kl);
  }
}

__global__ void k_final(const double* __restrict__ acc, float* __restrict__ out) {
  if (threadIdx.x == 0 && blockIdx.x == 0) {
    out[0] = (float)(acc[0] * (10.0 / (double)BB));
    out[1] = (float)(acc[1] * (0.5 / ((double)TT * (double)BB)));
    out[2] = (float)(acc[2] * (0.5 / ((double)TT * (double)KK)));
    out[3] = (float)(acc[3] * (0.5 / (double)BB));
    out[4] = (float)(acc[4] * (-0.01));
  }
}

// ---------------- host ----------------
extern "C" void kernel_launch(void* const* d_in, const int* in_sizes, int n_in,
                              void* d_out, int out_size, void* d_ws, size_t ws_size,
                              hipStream_t stream) {
  const float* normalized_bows = (const float*)d_in[0];
  const float* bow_t  = (const float*)d_in[1];
  const float* adj    = (const float*)d_in[2];
  const float* mu_q   = (const float*)d_in[3];
  const float* ls_q   = (const float*)d_in[4];
  const float* rho_W  = (const float*)d_in[5];
  const float* rho_b  = (const float*)d_in[6];
  const float* qt_W1  = (const float*)d_in[7];
  const float* qt_b1  = (const float*)d_in[8];
  const float* qt_W2  = (const float*)d_in[9];
  const float* qt_b2  = (const float*)d_in[10];
  const float* mut_W  = (const float*)d_in[11];
  const float* mut_b  = (const float*)d_in[12];
  const float* lst_W  = (const float*)d_in[13];
  const float* lst_b  = (const float*)d_in[14];
  const float* qe_W   = (const float*)d_in[15];
  const float* qe_b   = (const float*)d_in[16];
  const float* Wih    = (const float*)d_in[17];
  const float* Whh    = (const float*)d_in[18];
  const float* bih    = (const float*)d_in[19];
  const float* bhh    = (const float*)d_in[20];
  const float* mue_W  = (const float*)d_in[21];
  const float* mue_b  = (const float*)d_in[22];
  const float* lse_W  = (const float*)d_in[23];
  const float* lse_b  = (const float*)d_in[24];
  float* out = (float*)d_out;

  // -------- workspace layout (floats), lifetime-based arenas, ~55 MB --------
  double* acc = (double*)d_ws;
  float* base      = (float*)d_ws + 16;
  float* betaT_f   = base;                    // 1,500,000 fl = [5000][600] bf16 (whole run)
  float* alphas    = betaT_f + 1500000;       // 180,000
  float* alphbf_f  = alphas + 180000;         // 91,200 = [600][304] bf16
  float* arenaX    = alphbf_f + 91200;        // 3,145,728: logits (ph A) -> xg (ph B)
  float* arenaY    = arenaX + 3145728;        // 3,686,400: beta_bf (ph A) -> h1_bf + h2 (ph C)
  float* arenaZ    = arenaY + 3686400;        // 2,320,000: {rhoW,qeW,Wih}_bf -> {qtW1,qtW2}_bf
  float* inp       = arenaZ + 2320000;        // 786,432
  float* inpbf_f   = inp + 786432;            // 393,216
  float* sumbias   = inpbf_f + 393216;        // 1,024
  float* whhT      = sumbias + 1024;          // 262,144
  float* h_buf     = whhT + 262144;           // 65,536
  float* c_buf     = h_buf + 65536;           // 65,536
  float* lstm_out  = c_buf + 65536;           // 786,432
  float* etas      = lstm_out + 786432;       // 153,600
  float* bows_part = etas + 153600;           // 204,800
  float* thbf_f    = bows_part + 204800;      // 86,016 = [3072][56] bf16

  short* betaT    = (short*)betaT_f;
  short* alph_bf  = (short*)alphbf_f;
  float* logits   = arenaX;
  float* xg       = arenaX;
  short* beta_bf  = (short*)arenaY;
  short* h1_bf    = (short*)arenaY;
  float* h2       = arenaY + 1228800;
  short* rhoW_bf  = (short*)arenaZ;
  short* qeW_bf   = (short*)(arenaZ + 760000);
  short* Wih_bf   = (short*)(arenaZ + 1400000);
  short* qtW1_bf  = (short*)arenaZ;
  short* qtW2_bf  = (short*)(arenaZ + 2000000);
  short* inp_bf   = (short*)inpbf_f;
  short* theta_bf = (short*)thbf_f;

  // JAX keys: key(42) -> split(3)
  uint32_t e0a, e0b, e1a, e1b, e2a, e2b;
#if JAX_PARTITIONABLE
  threefry2x32(0u, 42u, 0u, 0u, e0a, e0b);
  threefry2x32(0u, 42u, 0u, 1u, e1a, e1b);
  threefry2x32(0u, 42u, 0u, 2u, e2a, e2b);
#else
  uint32_t r00, r01, r10, r11, r20, r21;
  threefry2x32(0u, 42u, 0u, 3u, r00, r01);
  threefry2x32(0u, 42u, 1u, 4u, r10, r11);
  threefry2x32(0u, 42u, 2u, 5u, r20, r21);
  e0a = r00; e0b = r10;
  e1a = r20; e1b = r01;
  e2a = r11; e2b = r21;
#endif

  hipMemsetAsync(acc, 0, 5 * sizeof(double), stream);

  // ---- alpha / beta path ----
  k_alphas<<<704, 256, 0, stream>>>(mu_q, ls_q, alphas, alph_bf, e0a, e0b);
  k_kld_alpha<<<704, 256, 0, stream>>>(mu_q, ls_q, alphas, acc);
  k_cvt2d<<<(1500000 + 255) / 256, 256, 0, stream>>>(rho_W, rhoW_bf, 5000, 300, 300, 304);
  mfma_gemm<0, 0><<<dim3(40, 5), 256, 0, stream>>>(alph_bf, rhoW_bf, logits, rho_b,
      nullptr, nullptr, 600, 5000, 300, 304, 304, 5000, 0, 0);
  k_softmax_bf<<<600, 256, 0, stream>>>(logits, beta_bf, 5000);
  k_transpose_bf<<<dim3(157, 19), 256, 0, stream>>>(beta_bf, betaT, 600, 5000);

  // ---- cond loss: sum(adj * betaT.betaT^T) ----
  mfma_gemm<2, 0><<<dim3(40, 40), 256, 0, stream>>>(betaT, betaT, nullptr, nullptr,
      adj, acc + 4, 5000, 5000, 600, 600, 600, 0, 0, 0);

  // ---- LSTM input path ----
  k_cvt<<<5000, 256, 0, stream>>>(qe_W, qeW_bf, 1280000);
  k_initbias<<<3072, 256, 0, stream>>>(inp, qe_b, 256, 786432);
  mfma_gemm<1, 1><<<dim3(2, 24, 8), 256, 0, stream>>>(bow_t, qeW_bf, inp, nullptr,
      nullptr, nullptr, 3072, 256, 5000, 5000, 5000, 256, 640, 0);
  k_cvt<<<3072, 256, 0, stream>>>(inp, inp_bf, 786432);
  k_bias_combine<<<4, 256, 0, stream>>>(bih, bhh, sumbias);
  k_cvt<<<1024, 256, 0, stream>>>(Wih, Wih_bf, 262144);
  mfma_gemm<0, 0><<<dim3(8, 24), 256, 0, stream>>>(inp_bf, Wih_bf, xg, sumbias,
      nullptr, nullptr, 3072, 1024, 256, 256, 256, 1024, 0, 0);
  k_transpose_whh<<<1024, 256, 0, stream>>>(Whh, whhT);

  for (int t = 0; t < TT; t++)
    k_lstm_step<<<64, 256, 0, stream>>>(xg, whhT, h_buf, c_buf, lstm_out, t, t == 0);
  for (int t = 0; t < TT; t++)
    k_eta_step<<<BB, 128, 0, stream>>>(lstm_out, mue_W, mue_b, lse_W, lse_b,
                                       etas, acc, t, e1a, e1b);

  // ---- theta encoder ----
  k_cvt2d<<<(4000000 + 255) / 256, 256, 0, stream>>>(qt_W1, qtW1_bf, 800, 5000, 5050, 5000);
  k_initbias<<<800, 256, 0, stream>>>(bows_part, qt_b1, 800, 204800);
  mfma_gemm<1, 1><<<dim3(7, 2, 8), 256, 0, stream>>>(normalized_bows, qtW1_bf, bows_part,
      nullptr, nullptr, nullptr, 256, 800, 5000, 5000, 5000, 800, 640, 0);
  k_h1<<<TT * BB, 256, 0, stream>>>(etas, qt_W1, bows_part, h1_bf);
  k_cvt<<<2500, 256, 0, stream>>>(qt_W2, qtW2_bf, 640000);
  mfma_gemm<0, 0><<<dim3(7, 24), 256, 0, stream>>>(h1_bf, qtW2_bf, h2, qt_b2,
      nullptr, nullptr, 3072, 800, 800, 800, 800, 800, 0, 1);
  k_theta<<<TT * BB, 128, 0, stream>>>(h2, mut_W, mut_b, lst_W, lst_b, etas,
                                       theta_bf, acc, e2a, e2b);

  // ---- decode + nll (fused GEMM-reduce, lik never materialized) ----
  mfma_gemm<3, 0><<<dim3(40, 2, 12), 256, 0, stream>>>(theta_bf, betaT, nullptr, nullptr,
      bow_t, acc + 0, 256, 5000, 50, 56, 600, 0, 0, 0);

  k_final<<<1, 64, 0, stream>>>(acc, out);
}

// Round 5
// 1386.741 us; speedup vs baseline: 3.4970x; 1.0990x over previous
//
#include <hip/hip_runtime.h>
#include <stdint.h>

// ---------------- problem constants ----------------
#define TT 12
#define KK 50
#define VV 5000
#define BB 256
#define RHO_ 300
#define HT_ 800
#define HE_ 256
#define LOG_DELTA -5.2983174f   // log(0.005)
#define DENOM0 (1.0f + 1e-6f)
#define DENOM1 (0.005f + 1e-6f)

typedef __attribute__((ext_vector_type(8))) short short8;
typedef __attribute__((ext_vector_type(4))) float f32x4;

// ---------------- threefry2x32 (matches jax._src.prng) ----------------
__host__ __device__ inline void threefry2x32(uint32_t k0, uint32_t k1,
                                             uint32_t x0, uint32_t x1,
                                             uint32_t& o0, uint32_t& o1) {
  uint32_t ks2 = k0 ^ k1 ^ 0x1BD11BDAu;
  x0 += k0; x1 += k1;
#define TF_RND(r) { x0 += x1; x1 = (x1 << r) | (x1 >> (32 - r)); x1 ^= x0; }
  TF_RND(13) TF_RND(15) TF_RND(26) TF_RND(6)  x0 += k1;  x1 += ks2 + 1u;
  TF_RND(17) TF_RND(29) TF_RND(16) TF_RND(24) x0 += ks2; x1 += k0 + 2u;
  TF_RND(13) TF_RND(15) TF_RND(26) TF_RND(6)  x0 += k0;  x1 += k1 + 3u;
  TF_RND(17) TF_RND(29) TF_RND(16) TF_RND(24) x0 += k1;  x1 += ks2 + 4u;
  TF_RND(13) TF_RND(15) TF_RND(26) TF_RND(6)  x0 += ks2; x1 += k0 + 5u;
#undef TF_RND
  o0 = x0; o1 = x1;
}

__device__ inline float erfinv_f(float x) {
  float w = -log1pf(-x * x);
  float p;
  if (w < 5.0f) {
    w -= 2.5f;
    p = 2.81022636e-08f;
    p = fmaf(p, w, 3.43273939e-07f);
    p = fmaf(p, w, -3.5233877e-06f);
    p = fmaf(p, w, -4.39150654e-06f);
    p = fmaf(p, w, 0.00021858087f);
    p = fmaf(p, w, -0.00125372503f);
    p = fmaf(p, w, -0.00417768164f);
    p = fmaf(p, w, 0.246640727f);
    p = fmaf(p, w, 1.50140941f);
  } else {
    w = sqrtf(w) - 3.0f;
    p = -0.000200214257f;
    p = fmaf(p, w, 0.000100950558f);
    p = fmaf(p, w, 0.00134934322f);
    p = fmaf(p, w, -0.00367342844f);
    p = fmaf(p, w, 0.00573950773f);
    p = fmaf(p, w, -0.0076224613f);
    p = fmaf(p, w, 0.00943887047f);
    p = fmaf(p, w, 1.00167406f);
    p = fmaf(p, w, 2.83297682f);
  }
  return p * x;
}

__device__ inline float jax_normal_f(uint32_t k0, uint32_t k1, uint32_t idx) {
  uint32_t o0, o1, bits;
  threefry2x32(k0, k1, 0u, idx, o0, o1);
  bits = o0 ^ o1;
  float f = __uint_as_float((bits >> 9) | 0x3f800000u) - 1.0f;
  const float lo = -0.99999994f;
  float u = fmaf(f, 2.0f, lo);
  u = fmaxf(lo, u);
  return 1.41421356f * erfinv_f(u);
}

__device__ inline float sigmoidf_(float x) { return 1.0f / (1.0f + expf(-x)); }

__device__ inline short f2bf(float f) {
  uint32_t x = __float_as_uint(f);
  uint32_t r = (x + 0x7fffu + ((x >> 16) & 1u)) >> 16;
  return (short)r;
}
__device__ inline float bf2f(short u) {
  return __uint_as_float(((uint32_t)(uint16_t)u) << 16);
}

__device__ inline void blockReduceAtomicAdd(float v, double* target, float* redbuf) {
  int lane = threadIdx.x & 63, wid = threadIdx.x >> 6;
  #pragma unroll
  for (int off = 32; off; off >>= 1) v += __shfl_down(v, off, 64);
  if (lane == 0) redbuf[wid] = v;
  __syncthreads();
  if (threadIdx.x == 0) {
    float tot = redbuf[0] + redbuf[1] + redbuf[2] + redbuf[3];
    atomicAdd(target, (double)tot);
  }
}

// ---------------- MFMA GEMM: C[M,N] = A[M,K] * B[N,K]^T, 128x128 tile ----------------
// MODE 0: store C (+bias,+relu)
// MODE 1: split-K atomicAdd into pre-initialized C
// MODE 2: s = sum(D * bf2f(aux[m*ldaux+n])) -> atomicAdd slot (split-K legal: linear in D)
// AF32: A source fp32 (converted to bf16 in staging); else A bf16.
template<int MODE, int AF32>
__global__ __launch_bounds__(256) void mfma_gemm(
    const void* __restrict__ Ap, const short* __restrict__ Bp,
    float* __restrict__ C, const float* __restrict__ bias,
    const short* __restrict__ aux, double* __restrict__ slot,
    int M, int N, int K, int lda, int ldb, int ldc, int ldaux,
    int kchunk, int relu)
{
  __shared__ alignas(16) short As[128 * 40];
  __shared__ alignas(16) short Bs[128 * 40];
  __shared__ float redg[4];
  int tid = threadIdx.x, lane = tid & 63, wv = tid >> 6;
  int wm = wv >> 1, wn = wv & 1;
  int quad = lane >> 4, l16 = lane & 15;
  int m0 = blockIdx.y * 128, n0 = blockIdx.x * 128;
  int kbeg = (kchunk > 0) ? (int)blockIdx.z * kchunk : 0;
  int kend = (kchunk > 0) ? min(K, kbeg + kchunk) : K;
  const short* Ab = (const short*)Ap;
  const float* Af = (const float*)Ap;

  f32x4 acc[16];
  #pragma unroll
  for (int i = 0; i < 16; i++) acc[i] = (f32x4){0.f, 0.f, 0.f, 0.f};

  int srow = tid >> 2, skc = (tid & 3) * 8;
  for (int k0 = kbeg; k0 < kend; k0 += 32) {
    #pragma unroll
    for (int p = 0; p < 2; p++) {
      int row = srow + p * 64;
      int gk = k0 + skc;
      int rem = kend - gk;
      short8 av = {0, 0, 0, 0, 0, 0, 0, 0};
      int gm = m0 + row;
      if (gm < M && rem > 0) {
        if (AF32) {
          const float* s = Af + (size_t)gm * lda + gk;
          if (rem >= 8) {
            float4 f0 = *(const float4*)(s);
            float4 f1 = *(const float4*)(s + 4);
            av[0] = f2bf(f0.x); av[1] = f2bf(f0.y); av[2] = f2bf(f0.z); av[3] = f2bf(f0.w);
            av[4] = f2bf(f1.x); av[5] = f2bf(f1.y); av[6] = f2bf(f1.z); av[7] = f2bf(f1.w);
          } else {
            for (int e = 0; e < 8; e++) if (e < rem) av[e] = f2bf(s[e]);
          }
        } else {
          const short* s = Ab + (size_t)gm * lda + gk;
          if (rem >= 8) {
            const uint32_t* u = (const uint32_t*)s;
            uint32_t u0 = u[0], u1 = u[1], u2 = u[2], u3 = u[3];
            av[0] = (short)u0; av[1] = (short)(u0 >> 16);
            av[2] = (short)u1; av[3] = (short)(u1 >> 16);
            av[4] = (short)u2; av[5] = (short)(u2 >> 16);
            av[6] = (short)u3; av[7] = (short)(u3 >> 16);
          } else {
            for (int e = 0; e < 8; e++) if (e < rem) av[e] = s[e];
          }
        }
      }
      *(short8*)(&As[row * 40 + skc]) = av;
      short8 bv = {0, 0, 0, 0, 0, 0, 0, 0};
      int gn = n0 + row;
      if (gn < N && rem > 0) {
        const short* s = Bp + (size_t)gn * ldb + gk;
        if (rem >= 8) {
          const uint32_t* u = (const uint32_t*)s;
          uint32_t u0 = u[0], u1 = u[1], u2 = u[2], u3 = u[3];
          bv[0] = (short)u0; bv[1] = (short)(u0 >> 16);
          bv[2] = (short)u1; bv[3] = (short)(u1 >> 16);
          bv[4] = (short)u2; bv[5] = (short)(u2 >> 16);
          bv[6] = (short)u3; bv[7] = (short)(u3 >> 16);
        } else {
          for (int e = 0; e < 8; e++) if (e < rem) bv[e] = s[e];
        }
      }
      *(short8*)(&Bs[row * 40 + skc]) = bv;
    }
    __syncthreads();
    short8 af[4], bfr[4];
    const short* ap = &As[(wm * 64 + l16) * 40 + quad * 8];
    const short* bp = &Bs[(wn * 64 + l16) * 40 + quad * 8];
    #pragma unroll
    for (int i = 0; i < 4; i++) af[i] = *(const short8*)(ap + i * 16 * 40);
    #pragma unroll
    for (int j = 0; j < 4; j++) bfr[j] = *(const short8*)(bp + j * 16 * 40);
    #pragma unroll
    for (int i = 0; i < 4; i++)
      #pragma unroll
      for (int j = 0; j < 4; j++)
        acc[i * 4 + j] = __builtin_amdgcn_mfma_f32_16x16x32_bf16(af[i], bfr[j], acc[i * 4 + j], 0, 0, 0);
    __syncthreads();
  }

  float s = 0.f;
  #pragma unroll
  for (int i = 0; i < 4; i++) {
    int gmb = m0 + wm * 64 + i * 16 + quad * 4;
    #pragma unroll
    for (int j = 0; j < 4; j++) {
      int gn = n0 + wn * 64 + j * 16 + l16;
      f32x4 v = acc[i * 4 + j];
      if (gn >= N) continue;
      if (MODE == 0) {
        float bs = bias ? bias[gn] : 0.f;
        #pragma unroll
        for (int r = 0; r < 4; r++) {
          int gm = gmb + r;
          if (gm < M) {
            float c = v[r] + bs;
            if (relu) c = fmaxf(c, 0.f);
            C[(size_t)gm * ldc + gn] = c;
          }
        }
      } else if (MODE == 1) {
        #pragma unroll
        for (int r = 0; r < 4; r++) {
          int gm = gmb + r;
          if (gm < M) atomicAdd(&C[(size_t)gm * ldc + gn], v[r]);
        }
      } else {
        #pragma unroll
        for (int r = 0; r < 4; r++) {
          int gm = gmb + r;
          if (gm < M) s += v[r] * bf2f(aux[(size_t)gm * ldaux + gn]);
        }
      }
    }
  }
  if (MODE == 2) {
    #pragma unroll
    for (int off = 32; off; off >>= 1) s += __shfl_down(s, off, 64);
    if (lane == 0) redg[wv] = s;
    __syncthreads();
    if (tid == 0) atomicAdd(slot, (double)(redg[0] + redg[1] + redg[2] + redg[3]));
  }
}

// ---------------- dedicated decode: 64x64 tile, K=50, fused -log(lik)*bow reduce ----
__global__ __launch_bounds__(256) void k_decode64(
    const short* __restrict__ theta_bf, const short* __restrict__ betaT,
    const float* __restrict__ bow_t, double* __restrict__ slot) {
  __shared__ alignas(16) short As[64 * 40];
  __shared__ alignas(16) short Bs[64 * 40];
  __shared__ float redg[4];
  int tid = threadIdx.x, lane = tid & 63, wv = tid >> 6;
  int wm = wv >> 1, wn = wv & 1;
  int quad = lane >> 4, l16 = lane & 15;
  int n0 = blockIdx.x * 64, m0 = blockIdx.y * 64, z = blockIdx.z;
  const short* A = theta_bf + (size_t)z * 256 * 56;

  f32x4 acc[2][2];
  #pragma unroll
  for (int i = 0; i < 2; i++)
    #pragma unroll
    for (int j = 0; j < 2; j++) acc[i][j] = (f32x4){0.f, 0.f, 0.f, 0.f};

  int srow = tid >> 2, skc = (tid & 3) * 8;
  #pragma unroll
  for (int k0 = 0; k0 < 64; k0 += 32) {
    int gk = k0 + skc, rem = KK - gk;
    short8 av = {0, 0, 0, 0, 0, 0, 0, 0};
    int gm = m0 + srow;
    if (rem > 0) {
      const short* s = A + (size_t)gm * 56 + gk;
      if (rem >= 8) {
        const uint32_t* u = (const uint32_t*)s;
        uint32_t u0 = u[0], u1 = u[1], u2 = u[2], u3 = u[3];
        av[0] = (short)u0; av[1] = (short)(u0 >> 16);
        av[2] = (short)u1; av[3] = (short)(u1 >> 16);
        av[4] = (short)u2; av[5] = (short)(u2 >> 16);
        av[6] = (short)u3; av[7] = (short)(u3 >> 16);
      } else {
        for (int e = 0; e < 8; e++) if (e < rem) av[e] = s[e];
      }
    }
    *(short8*)(&As[srow * 40 + skc]) = av;
    short8 bv = {0, 0, 0, 0, 0, 0, 0, 0};
    int gn = n0 + srow;
    if (gn < VV && rem > 0) {
      const short* s = betaT + (size_t)gn * 600 + z * KK + gk;
      if (rem >= 8) {
        const uint32_t* u = (const uint32_t*)s;
        uint32_t u0 = u[0], u1 = u[1], u2 = u[2], u3 = u[3];
        bv[0] = (short)u0; bv[1] = (short)(u0 >> 16);
        bv[2] = (short)u1; bv[3] = (short)(u1 >> 16);
        bv[4] = (short)u2; bv[5] = (short)(u2 >> 16);
        bv[6] = (short)u3; bv[7] = (short)(u3 >> 16);
      } else {
        for (int e = 0; e < 8; e++) if (e < rem) bv[e] = s[e];
      }
    }
    *(short8*)(&Bs[srow * 40 + skc]) = bv;
    __syncthreads();
    short8 af[2], bfr[2];
    #pragma unroll
    for (int i = 0; i < 2; i++) af[i] = *(const short8*)(&As[(wm * 32 + i * 16 + l16) * 40 + quad * 8]);
    #pragma unroll
    for (int j = 0; j < 2; j++) bfr[j] = *(const short8*)(&Bs[(wn * 32 + j * 16 + l16) * 40 + quad * 8]);
    #pragma unroll
    for (int i = 0; i < 2; i++)
      #pragma unroll
      for (int j = 0; j < 2; j++)
        acc[i][j] = __builtin_amdgcn_mfma_f32_16x16x32_bf16(af[i], bfr[j], acc[i][j], 0, 0, 0);
    __syncthreads();
  }

  float s = 0.f;
  #pragma unroll
  for (int i = 0; i < 2; i++) {
    int gmb = m0 + wm * 32 + i * 16 + quad * 4;
    #pragma unroll
    for (int j = 0; j < 2; j++) {
      int gn = n0 + wn * 32 + j * 16 + l16;
      if (gn >= VV) continue;
      f32x4 v = acc[i][j];
      #pragma unroll
      for (int r = 0; r < 4; r++) {
        int gm = gmb + r;
        s -= __logf(v[r] + 1e-6f) * bow_t[((size_t)gm * TT + z) * VV + gn];
      }
    }
  }
  #pragma unroll
  for (int off = 32; off; off >>= 1) s += __shfl_down(s, off, 64);
  if (lane == 0) redg[wv] = s;
  __syncthreads();
  if (tid == 0) atomicAdd(slot, (double)(redg[0] + redg[1] + redg[2] + redg[3]));
}

// ---------------- fused prep: all weight cvts / transposes / bias inits ----------------
__global__ void k_prep(const float* __restrict__ qe_W, const float* __restrict__ Wih,
                       const float* __restrict__ qt_W2, const float* __restrict__ qt_W1,
                       const float* __restrict__ rho_W, const float* __restrict__ Whh,
                       const float* __restrict__ bih, const float* __restrict__ bhh,
                       const float* __restrict__ qe_b, const float* __restrict__ qt_b1,
                       short* __restrict__ qeW_bf, short* __restrict__ Wih_bf,
                       short* __restrict__ qtW2_bf, short* __restrict__ qtW1_bf,
                       short* __restrict__ tail_bf, short* __restrict__ rhoW_bf,
                       float* __restrict__ whhT, float* __restrict__ sumbias,
                       float* __restrict__ inp, float* __restrict__ bows_part) {
  // N6 = 4*HE*HE = 262144 (Whh transpose)  -- was 1048576 in R3: OOB read of Whh -> GPU fault
  const int N0 = 1280000, N1 = 262144, N2 = 640000, N3 = 4000000, N4 = 40000,
            N5 = 1500000, N6 = 262144, N7 = 1024, N8 = 786432, N9 = 204800;
  const int total = N0 + N1 + N2 + N3 + N4 + N5 + N6 + N7 + N8 + N9;
  for (int i = blockIdx.x * 256 + threadIdx.x; i < total; i += gridDim.x * 256) {
    int idx = i;
    if (idx < N0) { qeW_bf[idx] = f2bf(qe_W[idx]); continue; }
    idx -= N0;
    if (idx < N1) { Wih_bf[idx] = f2bf(Wih[idx]); continue; }
    idx -= N1;
    if (idx < N2) { qtW2_bf[idx] = f2bf(qt_W2[idx]); continue; }
    idx -= N2;
    if (idx < N3) { int r = idx / VV, c = idx % VV;
      qtW1_bf[idx] = f2bf(qt_W1[(size_t)r * (VV + KK) + c]); continue; }
    idx -= N3;
    if (idx < N4) { int r = idx / KK, c = idx % KK;
      tail_bf[idx] = f2bf(qt_W1[(size_t)r * (VV + KK) + VV + c]); continue; }
    idx -= N4;
    if (idx < N5) { rhoW_bf[idx] = f2bf(rho_W[idx]); continue; }
    idx -= N5;
    if (idx < N6) { int h = idx >> 10, j = idx & 1023;   // h<256, j<1024
      whhT[idx] = Whh[(size_t)j * HE_ + h]; continue; }
    idx -= N6;
    if (idx < N7) { sumbias[idx] = bih[idx] + bhh[idx]; continue; }
    idx -= N7;
    if (idx < N8) { inp[idx] = qe_b[idx & 255]; continue; }
    idx -= N8;
    bows_part[idx] = qt_b1[idx % 800];
  }
}

// ---------------- alphas + fused kld_alpha ----------------
__global__ void k_alphas(const float* __restrict__ mu_q, const float* __restrict__ ls_q,
                         short* __restrict__ alph_bf, double* __restrict__ acc,
                         uint32_t ka, uint32_t kb) {
  __shared__ float red[4];
  int i = blockIdx.x * 256 + threadIdx.x;
  float kl = 0.f;
  if (i < TT * KK * RHO_) {
    int t = i / (KK * RHO_);
    int k = (i / RHO_) % KK;
    int r = i % RHO_;
    int src = k * (TT * RHO_) + t * RHO_ + r;
    float mu = mu_q[src], ls = ls_q[src];
    float eps = jax_normal_f(ka, kb, (uint32_t)i);
    float a = mu + eps * expf(0.5f * ls);
    alph_bf[i] = f2bf(a);
    float qls = fminf(fmaxf(ls, -100.f), 100.f);
    float pmu = 0.f, pls = 0.f, denom = DENOM0;
    if (t > 0) {
      int srcp = k * (TT * RHO_) + (t - 1) * RHO_ + r;
      float mup = mu_q[srcp], lsp = ls_q[srcp];
      float epsp = jax_normal_f(ka, kb, (uint32_t)(i - KK * RHO_));
      pmu = mup + epsp * expf(0.5f * lsp);
      pls = LOG_DELTA; denom = DENOM1;
    }
    float d = mu - pmu;
    kl = (expf(qls) + d * d) / denom - 1.0f + pls - qls;
  }
  blockReduceAtomicAdd(kl, &acc[2], red);
}

__global__ void k_softmax_bf(const float* __restrict__ in, short* __restrict__ out, int ncols) {
  int row = blockIdx.x;
  const float* d = in + (size_t)row * ncols;
  short* o = out + (size_t)row * ncols;
  int tid = threadIdx.x;
  __shared__ float red[256];
  float m = -INFINITY;
  for (int v = tid; v < ncols; v += 256) m = fmaxf(m, d[v]);
  red[tid] = m; __syncthreads();
  for (int s = 128; s; s >>= 1) { if (tid < s) red[tid] = fmaxf(red[tid], red[tid + s]); __syncthreads(); }
  float mx = red[0]; __syncthreads();
  float sum = 0.f;
  for (int v = tid; v < ncols; v += 256) sum += __expf(d[v] - mx);
  red[tid] = sum; __syncthreads();
  for (int s = 128; s; s >>= 1) { if (tid < s) red[tid] += red[tid + s]; __syncthreads(); }
  float inv = 1.0f / red[0];
  for (int v = tid; v < ncols; v += 256) o[v] = f2bf(__expf(d[v] - mx) * inv);
}

__global__ __launch_bounds__(256) void k_transpose_bf(const short* __restrict__ in,
                                                      short* __restrict__ out, int R, int Cc) {
  __shared__ short tile[32][33];
  int c0 = blockIdx.x * 32, r0 = blockIdx.y * 32;
  int tx = threadIdx.x & 31, ty = threadIdx.x >> 5;
  for (int rr = ty; rr < 32; rr += 8) {
    int r = r0 + rr, c = c0 + tx;
    tile[rr][tx] = (r < R && c < Cc) ? in[(size_t)r * Cc + c] : (short)0;
  }
  __syncthreads();
  for (int cc = ty; cc < 32; cc += 8) {
    int c = c0 + cc, r = r0 + tx;
    if (c < Cc && r < R) out[(size_t)c * R + r] = tile[tx][cc];
  }
}

// ---------------- fused LSTM: one launch, t-loop inside (batch-parallel) ----------------
__global__ __launch_bounds__(256) void k_lstm_all(
    const float* __restrict__ xg, const float* __restrict__ whhT,
    float* __restrict__ lstm_out) {
  __shared__ float hprev[4][256];
  __shared__ float g[4][1024];
  int tid = threadIdx.x;
  int b0 = blockIdx.x * 4;
  float c[4] = {0.f, 0.f, 0.f, 0.f};
  #pragma unroll
  for (int bb = 0; bb < 4; bb++) hprev[bb][tid] = 0.f;
  for (int t = 0; t < TT; t++) {
    __syncthreads();
    #pragma unroll
    for (int jj = 0; jj < 4; jj++) {
      int j = jj * 256 + tid;
      float a0 = 0, a1 = 0, a2 = 0, a3 = 0;
      for (int h = 0; h < 256; h++) {
        float w = whhT[(size_t)h * 1024 + j];
        a0 = fmaf(w, hprev[0][h], a0);
        a1 = fmaf(w, hprev[1][h], a1);
        a2 = fmaf(w, hprev[2][h], a2);
        a3 = fmaf(w, hprev[3][h], a3);
      }
      g[0][j] = xg[((size_t)(b0 + 0) * TT + t) * 1024 + j] + a0;
      g[1][j] = xg[((size_t)(b0 + 1) * TT + t) * 1024 + j] + a1;
      g[2][j] = xg[((size_t)(b0 + 2) * TT + t) * 1024 + j] + a2;
      g[3][j] = xg[((size_t)(b0 + 3) * TT + t) * 1024 + j] + a3;
    }
    __syncthreads();
    #pragma unroll
    for (int bb = 0; bb < 4; bb++) {
      float gi = g[bb][tid], gf = g[bb][256 + tid], gc = g[bb][512 + tid], go = g[bb][768 + tid];
      c[bb] = sigmoidf_(gf) * c[bb] + sigmoidf_(gi) * tanhf(gc);
      float h = sigmoidf_(go) * tanhf(c[bb]);
      hprev[bb][tid] = h;
      lstm_out[((size_t)t * BB + b0 + bb) * 256 + tid] = h;
    }
  }
}

// ---------------- fused eta scan: one launch, block per batch row ----------------
__global__ __launch_bounds__(128) void k_eta_all(
    const float* __restrict__ lstm_out, const float* __restrict__ mue_W,
    const float* __restrict__ mue_b, const float* __restrict__ lse_W,
    const float* __restrict__ lse_b, float* __restrict__ etas,
    double* __restrict__ acc, uint32_t ka, uint32_t kb) {
  int b = blockIdx.x, tid = threadIdx.x;
  __shared__ float z[HE_ + KK];
  __shared__ float mu_s[KK], ls_s[KK];
  float klsum = 0.f;
  if (tid < KK) z[HE_ + tid] = 0.f;
  for (int t = 0; t < TT; t++) {
    for (int i = tid; i < HE_; i += 128) z[i] = lstm_out[((size_t)t * BB + b) * HE_ + i];
    __syncthreads();
    if (tid < 100) {
      int j = tid % KK; bool isMu = tid < KK;
      const float* w = (isMu ? mue_W : lse_W) + (size_t)j * (HE_ + KK);
      float a = 0.f, a2 = 0.f;
      for (int i = 0; i < HE_ + KK; i += 2) {
        a = fmaf(z[i], w[i], a);
        a2 = fmaf(z[i + 1], w[i + 1], a2);
      }
      a += a2 + (isMu ? mue_b : lse_b)[j];
      if (isMu) mu_s[j] = a; else ls_s[j] = a;
    }
    __syncthreads();
    if (tid < KK) {
      float mu = mu_s[tid], ls = ls_s[tid];
      float eps = jax_normal_f(ka, kb, (uint32_t)((t * BB + b) * KK + tid));
      float eta = mu + eps * expf(0.5f * ls);
      float qls = fminf(fmaxf(ls, -100.f), 100.f);
      float pmu = z[HE_ + tid];
      float pls = (t == 0) ? 0.f : LOG_DELTA;
      float denom = (t == 0) ? DENOM0 : DENOM1;
      float d = mu - pmu;
      klsum += (expf(qls) + d * d) / denom - 1.0f + pls - qls;
      etas[((size_t)t * BB + b) * KK + tid] = eta;
      z[HE_ + tid] = eta;
    }
    __syncthreads();
  }
  if (tid < 64) {
    #pragma unroll
    for (int off = 32; off; off >>= 1) klsum += __shfl_down(klsum, off, 64);
    if (tid == 0) atomicAdd(&acc[3], (double)klsum);
  }
}

// ---------------- h1 tail: h1 = relu(bows_part + etas @ W1_tail^T) -> bf16 ----------------
__global__ __launch_bounds__(256) void k_h1(
    const float* __restrict__ etas, const short* __restrict__ tail_bf,
    const float* __restrict__ bows_part, short* __restrict__ h1_bf) {
  __shared__ float el[8][KK];
  int m0 = blockIdx.x * 8, tid = threadIdx.x;
  for (int idx = tid; idx < 8 * KK; idx += 256) {
    int mm = idx / KK, kk = idx % KK;
    el[mm][kk] = etas[(size_t)(m0 + mm) * KK + kk];
  }
  __syncthreads();
  for (int j = tid; j < HT_; j += 256) {
    const uint32_t* w = (const uint32_t*)(tail_bf + (size_t)j * KK);
    float wv[KK];
    #pragma unroll
    for (int k = 0; k < KK / 2; k++) {
      uint32_t u = w[k];
      wv[2 * k] = bf2f((short)u); wv[2 * k + 1] = bf2f((short)(u >> 16));
    }
    #pragma unroll
    for (int mm = 0; mm < 8; mm++) {
      int m = m0 + mm, b = m & (BB - 1);
      float a = bows_part[(size_t)b * HT_ + j];
      #pragma unroll
      for (int k = 0; k < KK; k++) a = fmaf(el[mm][k], wv[k], a);
      h1_bf[(size_t)m * HT_ + j] = f2bf(fmaxf(a, 0.f));
    }
  }
}

// ---------------- theta head ----------------
__global__ __launch_bounds__(128) void k_theta(
    const float* __restrict__ h2, const float* __restrict__ mut_W,
    const float* __restrict__ mut_b, const float* __restrict__ lst_W,
    const float* __restrict__ lst_b, const float* __restrict__ etas,
    short* __restrict__ theta_bf, double* __restrict__ acc, uint32_t ka, uint32_t kb) {
  int m = blockIdx.x;
  int tid = threadIdx.x;
  __shared__ float hr[HT_];
  __shared__ float mu_s[KK], ls_s[KK];
  for (int i = tid; i < HT_; i += 128) hr[i] = h2[(size_t)m * HT_ + i];
  __syncthreads();
  if (tid < 100) {
    int j = tid % KK; bool isMu = tid < KK;
    const float* w = (isMu ? mut_W : lst_W) + (size_t)j * HT_;
    float a = 0.f, a2 = 0.f;
    for (int i = 0; i < HT_; i += 2) {
      a = fmaf(hr[i], w[i], a);
      a2 = fmaf(hr[i + 1], w[i + 1], a2);
    }
    a += a2 + (isMu ? mut_b : lst_b)[j];
    if (isMu) mu_s[j] = a; else ls_s[j] = a;
  }
  __syncthreads();
  if (tid < 64) {
    float kl = 0.f, zv = -INFINITY;
    if (tid < KK) {
      float mu = mu_s[tid], ls = ls_s[tid];
      float eps = jax_normal_f(ka, kb, (uint32_t)(m * KK + tid));
      zv = mu + eps * expf(0.5f * ls);
      float qls = fminf(fmaxf(ls, -100.f), 100.f);
      float e = etas[(size_t)m * KK + tid];
      float d = mu - e;
      kl = (expf(qls) + d * d) / DENOM0 - 1.0f - qls;
    }
    float mx = zv;
    #pragma unroll
    for (int off = 32; off; off >>= 1) mx = fmaxf(mx, __shfl_xor(mx, off, 64));
    float ev = (tid < KK) ? expf(zv - mx) : 0.f;
    float sum = ev;
    #pragma unroll
    for (int off = 32; off; off >>= 1) sum += __shfl_xor(sum, off, 64);
    if (tid < KK) theta_bf[(size_t)m * 56 + tid] = f2bf(ev / sum);
    #pragma unroll
    for (int off = 32; off; off >>= 1) kl += __shfl_down(kl, off, 64);
    if (tid == 0) atomicAdd(&acc[1], (double)kl);
  }
}

__global__ void k_final(const double* __restrict__ acc, float* __restrict__ out) {
  if (threadIdx.x == 0 && blockIdx.x == 0) {
    out[0] = (float)(acc[0] * (10.0 / (double)BB));
    out[1] = (float)(acc[1] * (0.5 / ((double)TT * (double)BB)));
    out[2] = (float)(acc[2] * (0.5 / ((double)TT * (double)KK)));
    out[3] = (float)(acc[3] * (0.5 / (double)BB));
    out[4] = (float)(acc[4] * (-0.01));
  }
}

// ---------------- host ----------------
extern "C" void kernel_launch(void* const* d_in, const int* in_sizes, int n_in,
                              void* d_out, int out_size, void* d_ws, size_t ws_size,
                              hipStream_t stream) {
  const float* normalized_bows = (const float*)d_in[0];
  const float* bow_t  = (const float*)d_in[1];
  const float* adj    = (const float*)d_in[2];
  const float* mu_q   = (const float*)d_in[3];
  const float* ls_q   = (const float*)d_in[4];
  const float* rho_W  = (const float*)d_in[5];
  const float* rho_b  = (const float*)d_in[6];
  const float* qt_W1  = (const float*)d_in[7];
  const float* qt_b1  = (const float*)d_in[8];
  const float* qt_W2  = (const float*)d_in[9];
  const float* qt_b2  = (const float*)d_in[10];
  const float* mut_W  = (const float*)d_in[11];
  const float* mut_b  = (const float*)d_in[12];
  const float* lst_W  = (const float*)d_in[13];
  const float* lst_b  = (const float*)d_in[14];
  const float* qe_W   = (const float*)d_in[15];
  const float* qe_b   = (const float*)d_in[16];
  const float* Wih    = (const float*)d_in[17];
  const float* Whh    = (const float*)d_in[18];
  const float* bih    = (const float*)d_in[19];
  const float* bhh    = (const float*)d_in[20];
  const float* mue_W  = (const float*)d_in[21];
  const float* mue_b  = (const float*)d_in[22];
  const float* lse_W  = (const float*)d_in[23];
  const float* lse_b  = (const float*)d_in[24];
  float* out = (float*)d_out;

  // -------- workspace (floats; lifetime-overlapped; ~52.3 MB total) --------
  double* acc = (double*)d_ws;
  float* p          = (float*)d_ws + 16;
  float* betaT_f    = p;               p += 1500000;   // betaT  bf16 [5000][600]
  float* beta_bf_f  = p;               p += 1500000;   // beta   bf16 [600][5000]
  float* alphbf_f   = p;               p += 90000;     // alphas bf16 [600][300]
  float* rhoWbf_f   = p;               p += 750000;    // rho_W  bf16 [5000][300]
  float* arenaA     = p;               p += 3145728;   // logits f32 -> xg f32
  float* qeWbf_f    = p;               p += 640000;    // qe_W bf16
  float* Wihbf_f    = p;               p += 131072;    // Wih bf16
  float* arenaB     = p;               p += 2320000;   // qtW1_bf(2.0M)+qtW2_bf(0.32M); h1_bf overlays
  float* tailbf_f   = p;               p += 20000;     // qt_W1 tail bf16 [800][50]
  float* poolC      = p;               p += 2621440;   // inp|whhT|lstm_out -> h2 overlays
  float* sumbias    = p;               p += 1024;
  float* etas       = p;               p += 153600;
  float* bows_part  = p;               p += 204800;
  float* thbf_f     = p;               p += 86016;     // theta bf16 [3072][56]

  short* betaT    = (short*)betaT_f;
  short* beta_bf  = (short*)beta_bf_f;
  short* alph_bf  = (short*)alphbf_f;
  short* rhoW_bf  = (short*)rhoWbf_f;
  float* logits   = arenaA;
  float* xg       = arenaA;
  short* qeW_bf   = (short*)qeWbf_f;
  short* Wih_bf   = (short*)Wihbf_f;
  short* qtW1_bf  = (short*)arenaB;
  short* qtW2_bf  = (short*)(arenaB + 2000000);
  short* h1_bf    = (short*)arenaB;            // after qtW1 GEMM done
  short* tail_bf  = (short*)tailbf_f;
  float* inp      = poolC;
  float* whhT     = poolC + 786432;            // 262144 floats [256][1024]
  float* lstm_out = poolC + 786432 + 1048576;
  float* h2       = poolC;                     // after lstm/eta done
  short* theta_bf = (short*)thbf_f;

  // JAX keys: key(42) -> split(3)
  uint32_t e0a, e0b, e1a, e1b, e2a, e2b;
  threefry2x32(0u, 42u, 0u, 0u, e0a, e0b);
  threefry2x32(0u, 42u, 0u, 1u, e1a, e1b);
  threefry2x32(0u, 42u, 0u, 2u, e2a, e2b);

  (void)hipMemsetAsync(acc, 0, 5 * sizeof(double), stream);

  // all weight conversions / transposes / bias inits in one kernel
  k_prep<<<8192, 256, 0, stream>>>(qe_W, Wih, qt_W2, qt_W1, rho_W, Whh, bih, bhh,
                                   qe_b, qt_b1,
                                   qeW_bf, Wih_bf, qtW2_bf, qtW1_bf, tail_bf, rhoW_bf,
                                   whhT, sumbias, inp, bows_part);

  // alphas (+ fused kld_alpha)
  k_alphas<<<704, 256, 0, stream>>>(mu_q, ls_q, alph_bf, acc, e0a, e0b);

  // beta = softmax(alphas @ rho_W^T + rho_b); bf16 row-major + transposed copy
  mfma_gemm<0, 0><<<dim3(40, 5), 256, 0, stream>>>(alph_bf, rhoW_bf, logits, rho_b,
      nullptr, nullptr, 600, VV, RHO_, RHO_, RHO_, VV, 0, 0, 0);
  k_softmax_bf<<<600, 256, 0, stream>>>(logits, beta_bf, VV);
  k_transpose_bf<<<dim3(157, 19), 256, 0, stream>>>(beta_bf, betaT, 600, VV);

  // cond = sum over (v,r) of betaT[v,r] * (adj @ beta^T)[v,r]; split-K (linear epilogue)
  mfma_gemm<2, 1><<<dim3(5, 40, 4), 256, 0, stream>>>(adj, beta_bf, nullptr, nullptr,
      betaT, acc + 4, VV, 600, VV, VV, VV, 0, 600, 1280, 0);

  // inp = bow_t @ qe_W^T + qe_b (split-K atomic into bias-initialized inp)
  mfma_gemm<1, 1><<<dim3(2, 24, 8), 256, 0, stream>>>(bow_t, qeW_bf, inp, nullptr,
      nullptr, nullptr, 3072, HE_, VV, VV, VV, HE_, 0, 640, 0);
  // xg = inp @ Wih^T + (bih + bhh)
  mfma_gemm<0, 1><<<dim3(8, 24), 256, 0, stream>>>(inp, Wih_bf, xg, sumbias,
      nullptr, nullptr, 3072, 1024, HE_, HE_, HE_, 1024, 0, 0, 0);

  // fused scans
  k_lstm_all<<<64, 256, 0, stream>>>(xg, whhT, lstm_out);
  k_eta_all<<<BB, 128, 0, stream>>>(lstm_out, mue_W, mue_b, lse_W, lse_b, etas, acc, e1a, e1b);

  // theta encoder
  mfma_gemm<1, 1><<<dim3(7, 2, 8), 256, 0, stream>>>(normalized_bows, qtW1_bf, bows_part,
      nullptr, nullptr, nullptr, BB, HT_, VV, VV, VV, HT_, 0, 640, 0);
  k_h1<<<384, 256, 0, stream>>>(etas, tail_bf, bows_part, h1_bf);
  mfma_gemm<0, 0><<<dim3(7, 24), 256, 0, stream>>>(h1_bf, qtW2_bf, h2, qt_b2,
      nullptr, nullptr, 3072, HT_, HT_, HT_, HT_, HT_, 0, 0, 1);
  k_theta<<<3072, 128, 0, stream>>>(h2, mut_W, mut_b, lst_W, lst_b, etas,
                                    theta_bf, acc, e2a, e2b);

  // decode + nll
  k_decode64<<<dim3(79, 4, 12), 256, 0, stream>>>(theta_bf, betaT, bow_t, acc);

  k_final<<<1, 64, 0, stream>>>(acc, out);
}

// Round 6
// 1065.055 us; speedup vs baseline: 4.5532x; 1.3020x over previous
//
#include <hip/hip_runtime.h>
#include <stdint.h>

// ---------------- problem constants ----------------
#define TT 12
#define KK 50
#define VV 5000
#define BB 256
#define RHO_ 300
#define HT_ 800
#define HE_ 256
#define LOG_DELTA -5.2983174f   // log(0.005)
#define DENOM0 (1.0f + 1e-6f)
#define DENOM1 (0.005f + 1e-6f)

typedef __attribute__((ext_vector_type(8))) short short8;
typedef __attribute__((ext_vector_type(4))) float f32x4;

// ---------------- threefry2x32 (matches jax._src.prng) ----------------
__host__ __device__ inline void threefry2x32(uint32_t k0, uint32_t k1,
                                             uint32_t x0, uint32_t x1,
                                             uint32_t& o0, uint32_t& o1) {
  uint32_t ks2 = k0 ^ k1 ^ 0x1BD11BDAu;
  x0 += k0; x1 += k1;
#define TF_RND(r) { x0 += x1; x1 = (x1 << r) | (x1 >> (32 - r)); x1 ^= x0; }
  TF_RND(13) TF_RND(15) TF_RND(26) TF_RND(6)  x0 += k1;  x1 += ks2 + 1u;
  TF_RND(17) TF_RND(29) TF_RND(16) TF_RND(24) x0 += ks2; x1 += k0 + 2u;
  TF_RND(13) TF_RND(15) TF_RND(26) TF_RND(6)  x0 += k0;  x1 += k1 + 3u;
  TF_RND(17) TF_RND(29) TF_RND(16) TF_RND(24) x0 += k1;  x1 += ks2 + 4u;
  TF_RND(13) TF_RND(15) TF_RND(26) TF_RND(6)  x0 += ks2; x1 += k0 + 5u;
#undef TF_RND
  o0 = x0; o1 = x1;
}

__device__ inline float erfinv_f(float x) {
  float w = -log1pf(-x * x);
  float p;
  if (w < 5.0f) {
    w -= 2.5f;
    p = 2.81022636e-08f;
    p = fmaf(p, w, 3.43273939e-07f);
    p = fmaf(p, w, -3.5233877e-06f);
    p = fmaf(p, w, -4.39150654e-06f);
    p = fmaf(p, w, 0.00021858087f);
    p = fmaf(p, w, -0.00125372503f);
    p = fmaf(p, w, -0.00417768164f);
    p = fmaf(p, w, 0.246640727f);
    p = fmaf(p, w, 1.50140941f);
  } else {
    w = sqrtf(w) - 3.0f;
    p = -0.000200214257f;
    p = fmaf(p, w, 0.000100950558f);
    p = fmaf(p, w, 0.00134934322f);
    p = fmaf(p, w, -0.00367342844f);
    p = fmaf(p, w, 0.00573950773f);
    p = fmaf(p, w, -0.0076224613f);
    p = fmaf(p, w, 0.00943887047f);
    p = fmaf(p, w, 1.00167406f);
    p = fmaf(p, w, 2.83297682f);
  }
  return p * x;
}

__device__ inline float jax_normal_f(uint32_t k0, uint32_t k1, uint32_t idx) {
  uint32_t o0, o1, bits;
  threefry2x32(k0, k1, 0u, idx, o0, o1);
  bits = o0 ^ o1;
  float f = __uint_as_float((bits >> 9) | 0x3f800000u) - 1.0f;
  const float lo = -0.99999994f;
  float u = fmaf(f, 2.0f, lo);
  u = fmaxf(lo, u);
  return 1.41421356f * erfinv_f(u);
}

__device__ inline float sigmoidf_(float x) { return 1.0f / (1.0f + expf(-x)); }

__device__ inline short f2bf(float f) {
  uint32_t x = __float_as_uint(f);
  uint32_t r = (x + 0x7fffu + ((x >> 16) & 1u)) >> 16;
  return (short)r;
}
__device__ inline float bf2f(short u) {
  return __uint_as_float(((uint32_t)(uint16_t)u) << 16);
}

__device__ inline void blockReduceAtomicAdd(float v, double* target, float* redbuf) {
  int lane = threadIdx.x & 63, wid = threadIdx.x >> 6;
  #pragma unroll
  for (int off = 32; off; off >>= 1) v += __shfl_down(v, off, 64);
  if (lane == 0) redbuf[wid] = v;
  __syncthreads();
  if (threadIdx.x == 0) {
    float tot = redbuf[0] + redbuf[1] + redbuf[2] + redbuf[3];
    atomicAdd(target, (double)tot);
  }
}

// ---------------- MFMA GEMM: C[M,N] = A[M,K] * B[N,K]^T, 128x128 tile ----------------
// MODE 0: store C (+bias,+relu)
// MODE 1: split-K atomicAdd into pre-initialized C
// MODE 2: s = sum(D * bf2f(aux[m*ldaux+n])) -> atomicAdd slot (split-K legal: linear in D)
// AF32: A source fp32 (converted to bf16 in staging); else A bf16.
template<int MODE, int AF32>
__global__ __launch_bounds__(256) void mfma_gemm(
    const void* __restrict__ Ap, const short* __restrict__ Bp,
    float* __restrict__ C, const float* __restrict__ bias,
    const short* __restrict__ aux, double* __restrict__ slot,
    int M, int N, int K, int lda, int ldb, int ldc, int ldaux,
    int kchunk, int relu)
{
  __shared__ alignas(16) short As[128 * 40];
  __shared__ alignas(16) short Bs[128 * 40];
  __shared__ float redg[4];
  int tid = threadIdx.x, lane = tid & 63, wv = tid >> 6;
  int wm = wv >> 1, wn = wv & 1;
  int quad = lane >> 4, l16 = lane & 15;
  int m0 = blockIdx.y * 128, n0 = blockIdx.x * 128;
  int kbeg = (kchunk > 0) ? (int)blockIdx.z * kchunk : 0;
  int kend = (kchunk > 0) ? min(K, kbeg + kchunk) : K;
  const short* Ab = (const short*)Ap;
  const float* Af = (const float*)Ap;

  f32x4 acc[16];
  #pragma unroll
  for (int i = 0; i < 16; i++) acc[i] = (f32x4){0.f, 0.f, 0.f, 0.f};

  int srow = tid >> 2, skc = (tid & 3) * 8;
  for (int k0 = kbeg; k0 < kend; k0 += 32) {
    #pragma unroll
    for (int p = 0; p < 2; p++) {
      int row = srow + p * 64;
      int gk = k0 + skc;
      int rem = kend - gk;
      short8 av = {0, 0, 0, 0, 0, 0, 0, 0};
      int gm = m0 + row;
      if (gm < M && rem > 0) {
        if (AF32) {
          const float* s = Af + (size_t)gm * lda + gk;
          if (rem >= 8) {
            float4 f0 = *(const float4*)(s);
            float4 f1 = *(const float4*)(s + 4);
            av[0] = f2bf(f0.x); av[1] = f2bf(f0.y); av[2] = f2bf(f0.z); av[3] = f2bf(f0.w);
            av[4] = f2bf(f1.x); av[5] = f2bf(f1.y); av[6] = f2bf(f1.z); av[7] = f2bf(f1.w);
          } else {
            for (int e = 0; e < 8; e++) if (e < rem) av[e] = f2bf(s[e]);
          }
        } else {
          const short* s = Ab + (size_t)gm * lda + gk;
          if (rem >= 8) {
            const uint32_t* u = (const uint32_t*)s;
            uint32_t u0 = u[0], u1 = u[1], u2 = u[2], u3 = u[3];
            av[0] = (short)u0; av[1] = (short)(u0 >> 16);
            av[2] = (short)u1; av[3] = (short)(u1 >> 16);
            av[4] = (short)u2; av[5] = (short)(u2 >> 16);
            av[6] = (short)u3; av[7] = (short)(u3 >> 16);
          } else {
            for (int e = 0; e < 8; e++) if (e < rem) av[e] = s[e];
          }
        }
      }
      *(short8*)(&As[row * 40 + skc]) = av;
      short8 bv = {0, 0, 0, 0, 0, 0, 0, 0};
      int gn = n0 + row;
      if (gn < N && rem > 0) {
        const short* s = Bp + (size_t)gn * ldb + gk;
        if (rem >= 8) {
          const uint32_t* u = (const uint32_t*)s;
          uint32_t u0 = u[0], u1 = u[1], u2 = u[2], u3 = u[3];
          bv[0] = (short)u0; bv[1] = (short)(u0 >> 16);
          bv[2] = (short)u1; bv[3] = (short)(u1 >> 16);
          bv[4] = (short)u2; bv[5] = (short)(u2 >> 16);
          bv[6] = (short)u3; bv[7] = (short)(u3 >> 16);
        } else {
          for (int e = 0; e < 8; e++) if (e < rem) bv[e] = s[e];
        }
      }
      *(short8*)(&Bs[row * 40 + skc]) = bv;
    }
    __syncthreads();
    short8 af[4], bfr[4];
    const short* ap = &As[(wm * 64 + l16) * 40 + quad * 8];
    const short* bp = &Bs[(wn * 64 + l16) * 40 + quad * 8];
    #pragma unroll
    for (int i = 0; i < 4; i++) af[i] = *(const short8*)(ap + i * 16 * 40);
    #pragma unroll
    for (int j = 0; j < 4; j++) bfr[j] = *(const short8*)(bp + j * 16 * 40);
    #pragma unroll
    for (int i = 0; i < 4; i++)
      #pragma unroll
      for (int j = 0; j < 4; j++)
        acc[i * 4 + j] = __builtin_amdgcn_mfma_f32_16x16x32_bf16(af[i], bfr[j], acc[i * 4 + j], 0, 0, 0);
    __syncthreads();
  }

  float s = 0.f;
  #pragma unroll
  for (int i = 0; i < 4; i++) {
    int gmb = m0 + wm * 64 + i * 16 + quad * 4;
    #pragma unroll
    for (int j = 0; j < 4; j++) {
      int gn = n0 + wn * 64 + j * 16 + l16;
      f32x4 v = acc[i * 4 + j];
      if (gn >= N) continue;
      if (MODE == 0) {
        float bs = bias ? bias[gn] : 0.f;
        #pragma unroll
        for (int r = 0; r < 4; r++) {
          int gm = gmb + r;
          if (gm < M) {
            float c = v[r] + bs;
            if (relu) c = fmaxf(c, 0.f);
            C[(size_t)gm * ldc + gn] = c;
          }
        }
      } else if (MODE == 1) {
        #pragma unroll
        for (int r = 0; r < 4; r++) {
          int gm = gmb + r;
          if (gm < M) atomicAdd(&C[(size_t)gm * ldc + gn], v[r]);
        }
      } else {
        #pragma unroll
        for (int r = 0; r < 4; r++) {
          int gm = gmb + r;
          if (gm < M) s += v[r] * bf2f(aux[(size_t)gm * ldaux + gn]);
        }
      }
    }
  }
  if (MODE == 2) {
    #pragma unroll
    for (int off = 32; off; off >>= 1) s += __shfl_down(s, off, 64);
    if (lane == 0) redg[wv] = s;
    __syncthreads();
    if (tid == 0) atomicAdd(slot, (double)(redg[0] + redg[1] + redg[2] + redg[3]));
  }
}

// ---------------- dedicated decode: 64x64 tile, K=50, fused -log(lik)*bow reduce ----
__global__ __launch_bounds__(256) void k_decode64(
    const short* __restrict__ theta_bf, const short* __restrict__ betaT,
    const float* __restrict__ bow_t, double* __restrict__ slot) {
  __shared__ alignas(16) short As[64 * 40];
  __shared__ alignas(16) short Bs[64 * 40];
  __shared__ float redg[4];
  int tid = threadIdx.x, lane = tid & 63, wv = tid >> 6;
  int wm = wv >> 1, wn = wv & 1;
  int quad = lane >> 4, l16 = lane & 15;
  int n0 = blockIdx.x * 64, m0 = blockIdx.y * 64, z = blockIdx.z;
  const short* A = theta_bf + (size_t)z * 256 * 56;

  f32x4 acc[2][2];
  #pragma unroll
  for (int i = 0; i < 2; i++)
    #pragma unroll
    for (int j = 0; j < 2; j++) acc[i][j] = (f32x4){0.f, 0.f, 0.f, 0.f};

  int srow = tid >> 2, skc = (tid & 3) * 8;
  #pragma unroll
  for (int k0 = 0; k0 < 64; k0 += 32) {
    int gk = k0 + skc, rem = KK - gk;
    short8 av = {0, 0, 0, 0, 0, 0, 0, 0};
    int gm = m0 + srow;
    if (rem > 0) {
      const short* s = A + (size_t)gm * 56 + gk;
      if (rem >= 8) {
        const uint32_t* u = (const uint32_t*)s;
        uint32_t u0 = u[0], u1 = u[1], u2 = u[2], u3 = u[3];
        av[0] = (short)u0; av[1] = (short)(u0 >> 16);
        av[2] = (short)u1; av[3] = (short)(u1 >> 16);
        av[4] = (short)u2; av[5] = (short)(u2 >> 16);
        av[6] = (short)u3; av[7] = (short)(u3 >> 16);
      } else {
        for (int e = 0; e < 8; e++) if (e < rem) av[e] = s[e];
      }
    }
    *(short8*)(&As[srow * 40 + skc]) = av;
    short8 bv = {0, 0, 0, 0, 0, 0, 0, 0};
    int gn = n0 + srow;
    if (gn < VV && rem > 0) {
      const short* s = betaT + (size_t)gn * 600 + z * KK + gk;
      if (rem >= 8) {
        const uint32_t* u = (const uint32_t*)s;
        uint32_t u0 = u[0], u1 = u[1], u2 = u[2], u3 = u[3];
        bv[0] = (short)u0; bv[1] = (short)(u0 >> 16);
        bv[2] = (short)u1; bv[3] = (short)(u1 >> 16);
        bv[4] = (short)u2; bv[5] = (short)(u2 >> 16);
        bv[6] = (short)u3; bv[7] = (short)(u3 >> 16);
      } else {
        for (int e = 0; e < 8; e++) if (e < rem) bv[e] = s[e];
      }
    }
    *(short8*)(&Bs[srow * 40 + skc]) = bv;
    __syncthreads();
    short8 af[2], bfr[2];
    #pragma unroll
    for (int i = 0; i < 2; i++) af[i] = *(const short8*)(&As[(wm * 32 + i * 16 + l16) * 40 + quad * 8]);
    #pragma unroll
    for (int j = 0; j < 2; j++) bfr[j] = *(const short8*)(&Bs[(wn * 32 + j * 16 + l16) * 40 + quad * 8]);
    #pragma unroll
    for (int i = 0; i < 2; i++)
      #pragma unroll
      for (int j = 0; j < 2; j++)
        acc[i][j] = __builtin_amdgcn_mfma_f32_16x16x32_bf16(af[i], bfr[j], acc[i][j], 0, 0, 0);
    __syncthreads();
  }

  float s = 0.f;
  #pragma unroll
  for (int i = 0; i < 2; i++) {
    int gmb = m0 + wm * 32 + i * 16 + quad * 4;
    #pragma unroll
    for (int j = 0; j < 2; j++) {
      int gn = n0 + wn * 32 + j * 16 + l16;
      if (gn >= VV) continue;
      f32x4 v = acc[i][j];
      #pragma unroll
      for (int r = 0; r < 4; r++) {
        int gm = gmb + r;
        s -= __logf(v[r] + 1e-6f) * bow_t[((size_t)gm * TT + z) * VV + gn];
      }
    }
  }
  #pragma unroll
  for (int off = 32; off; off >>= 1) s += __shfl_down(s, off, 64);
  if (lane == 0) redg[wv] = s;
  __syncthreads();
  if (tid == 0) atomicAdd(slot, (double)(redg[0] + redg[1] + redg[2] + redg[3]));
}

// ---------------- fused prep: all weight cvts / transposes / bias inits ----------------
__global__ void k_prep(const float* __restrict__ qe_W, const float* __restrict__ Wih,
                       const float* __restrict__ qt_W2, const float* __restrict__ qt_W1,
                       const float* __restrict__ rho_W, const float* __restrict__ Whh,
                       const float* __restrict__ bih, const float* __restrict__ bhh,
                       const float* __restrict__ qe_b, const float* __restrict__ qt_b1,
                       const float* __restrict__ mut_W, const float* __restrict__ mut_b,
                       const float* __restrict__ lst_W, const float* __restrict__ lst_b,
                       short* __restrict__ qeW_bf, short* __restrict__ Wih_bf,
                       short* __restrict__ qtW2_bf, short* __restrict__ qtW1_bf,
                       short* __restrict__ tail_bf, short* __restrict__ rhoW_bf,
                       float* __restrict__ whhT, float* __restrict__ sumbias,
                       float* __restrict__ inp, float* __restrict__ bows_part,
                       short* __restrict__ headW_bf, float* __restrict__ head_b) {
  const int N0 = 1280000, N1 = 262144, N2 = 640000, N3 = 4000000, N4 = 40000,
            N5 = 1500000, N6 = 262144, N7 = 1024, N8 = 786432, N9 = 204800,
            N10 = 80000, N11 = 100;
  const int total = N0 + N1 + N2 + N3 + N4 + N5 + N6 + N7 + N8 + N9 + N10 + N11;
  for (int i = blockIdx.x * 256 + threadIdx.x; i < total; i += gridDim.x * 256) {
    int idx = i;
    if (idx < N0) { qeW_bf[idx] = f2bf(qe_W[idx]); continue; }
    idx -= N0;
    if (idx < N1) { Wih_bf[idx] = f2bf(Wih[idx]); continue; }
    idx -= N1;
    if (idx < N2) { qtW2_bf[idx] = f2bf(qt_W2[idx]); continue; }
    idx -= N2;
    if (idx < N3) { int r = idx / VV, c = idx % VV;
      qtW1_bf[idx] = f2bf(qt_W1[(size_t)r * (VV + KK) + c]); continue; }
    idx -= N3;
    if (idx < N4) { int r = idx / KK, c = idx % KK;
      tail_bf[idx] = f2bf(qt_W1[(size_t)r * (VV + KK) + VV + c]); continue; }
    idx -= N4;
    if (idx < N5) { rhoW_bf[idx] = f2bf(rho_W[idx]); continue; }
    idx -= N5;
    if (idx < N6) { int h = idx >> 10, j = idx & 1023;   // h<256, j<1024
      whhT[idx] = Whh[(size_t)j * HE_ + h]; continue; }
    idx -= N6;
    if (idx < N7) { sumbias[idx] = bih[idx] + bhh[idx]; continue; }
    idx -= N7;
    if (idx < N8) { inp[idx] = qe_b[idx & 255]; continue; }
    idx -= N8;
    if (idx < N9) { bows_part[idx] = qt_b1[idx % 800]; continue; }
    idx -= N9;
    if (idx < N10) { int r = idx / HT_, c = idx % HT_;
      headW_bf[idx] = f2bf(r < KK ? mut_W[(size_t)r * HT_ + c]
                                  : lst_W[(size_t)(r - KK) * HT_ + c]); continue; }
    idx -= N10;
    head_b[idx] = (idx < KK) ? mut_b[idx] : lst_b[idx - KK];
  }
}

// ---------------- alphas + fused kld_alpha ----------------
__global__ void k_alphas(const float* __restrict__ mu_q, const float* __restrict__ ls_q,
                         short* __restrict__ alph_bf, double* __restrict__ acc,
                         uint32_t ka, uint32_t kb) {
  __shared__ float red[4];
  int i = blockIdx.x * 256 + threadIdx.x;
  float kl = 0.f;
  if (i < TT * KK * RHO_) {
    int t = i / (KK * RHO_);
    int k = (i / RHO_) % KK;
    int r = i % RHO_;
    int src = k * (TT * RHO_) + t * RHO_ + r;
    float mu = mu_q[src], ls = ls_q[src];
    float eps = jax_normal_f(ka, kb, (uint32_t)i);
    float a = mu + eps * expf(0.5f * ls);
    alph_bf[i] = f2bf(a);
    float qls = fminf(fmaxf(ls, -100.f), 100.f);
    float pmu = 0.f, pls = 0.f, denom = DENOM0;
    if (t > 0) {
      int srcp = k * (TT * RHO_) + (t - 1) * RHO_ + r;
      float mup = mu_q[srcp], lsp = ls_q[srcp];
      float epsp = jax_normal_f(ka, kb, (uint32_t)(i - KK * RHO_));
      pmu = mup + epsp * expf(0.5f * lsp);
      pls = LOG_DELTA; denom = DENOM1;
    }
    float d = mu - pmu;
    kl = (expf(qls) + d * d) / denom - 1.0f + pls - qls;
  }
  blockReduceAtomicAdd(kl, &acc[2], red);
}

__global__ void k_softmax_bf(const float* __restrict__ in, short* __restrict__ out, int ncols) {
  int row = blockIdx.x;
  const float* d = in + (size_t)row * ncols;
  short* o = out + (size_t)row * ncols;
  int tid = threadIdx.x;
  __shared__ float red[256];
  float m = -INFINITY;
  for (int v = tid; v < ncols; v += 256) m = fmaxf(m, d[v]);
  red[tid] = m; __syncthreads();
  for (int s = 128; s; s >>= 1) { if (tid < s) red[tid] = fmaxf(red[tid], red[tid + s]); __syncthreads(); }
  float mx = red[0]; __syncthreads();
  float sum = 0.f;
  for (int v = tid; v < ncols; v += 256) sum += __expf(d[v] - mx);
  red[tid] = sum; __syncthreads();
  for (int s = 128; s; s >>= 1) { if (tid < s) red[tid] += red[tid + s]; __syncthreads(); }
  float inv = 1.0f / red[0];
  for (int v = tid; v < ncols; v += 256) o[v] = f2bf(__expf(d[v] - mx) * inv);
}

__global__ __launch_bounds__(256) void k_transpose_bf(const short* __restrict__ in,
                                                      short* __restrict__ out, int R, int Cc) {
  __shared__ short tile[32][33];
  int c0 = blockIdx.x * 32, r0 = blockIdx.y * 32;
  int tx = threadIdx.x & 31, ty = threadIdx.x >> 5;
  for (int rr = ty; rr < 32; rr += 8) {
    int r = r0 + rr, c = c0 + tx;
    tile[rr][tx] = (r < R && c < Cc) ? in[(size_t)r * Cc + c] : (short)0;
  }
  __syncthreads();
  for (int cc = ty; cc < 32; cc += 8) {
    int c = c0 + cc, r = r0 + tx;
    if (c < Cc && r < R) out[(size_t)c * R + r] = tile[tx][cc];
  }
}

// ---------------- fused LSTM: 64 blocks x 1024 threads, j-per-thread ----------------
// block handles 4 batch rows; waves 0-3 (tid<256) own cell state c[4] in registers.
__global__ __launch_bounds__(1024) void k_lstm_all(
    const float* __restrict__ xg, const float* __restrict__ whhT,
    float* __restrict__ lstm_out) {
  __shared__ float hprev[4][256];
  __shared__ float g_s[4][1024];
  int tid = threadIdx.x;            // j = gate column 0..1023
  int b0 = blockIdx.x * 4;
  float c[4] = {0.f, 0.f, 0.f, 0.f};
  if (tid < 256) {
    #pragma unroll
    for (int bb = 0; bb < 4; bb++) hprev[bb][tid] = 0.f;
  }
  __syncthreads();
  for (int t = 0; t < TT; t++) {
    float a0 = 0.f, a1 = 0.f, a2 = 0.f, a3 = 0.f;
    #pragma unroll 8
    for (int h = 0; h < 256; h++) {
      float w = whhT[(size_t)h * 1024 + tid];
      a0 = fmaf(w, hprev[0][h], a0);
      a1 = fmaf(w, hprev[1][h], a1);
      a2 = fmaf(w, hprev[2][h], a2);
      a3 = fmaf(w, hprev[3][h], a3);
    }
    __syncthreads();   // everyone done reading hprev for this t
    g_s[0][tid] = xg[((size_t)(b0 + 0) * TT + t) * 1024 + tid] + a0;
    g_s[1][tid] = xg[((size_t)(b0 + 1) * TT + t) * 1024 + tid] + a1;
    g_s[2][tid] = xg[((size_t)(b0 + 2) * TT + t) * 1024 + tid] + a2;
    g_s[3][tid] = xg[((size_t)(b0 + 3) * TT + t) * 1024 + tid] + a3;
    __syncthreads();
    if (tid < 256) {
      #pragma unroll
      for (int bb = 0; bb < 4; bb++) {
        float gi = g_s[bb][tid], gf = g_s[bb][256 + tid];
        float gc = g_s[bb][512 + tid], go = g_s[bb][768 + tid];
        c[bb] = sigmoidf_(gf) * c[bb] + sigmoidf_(gi) * tanhf(gc);
        float h = sigmoidf_(go) * tanhf(c[bb]);
        hprev[bb][tid] = h;
        lstm_out[((size_t)t * BB + b0 + bb) * 256 + tid] = h;
      }
    }
    __syncthreads();
  }
}

// ---------------- fused eta scan: LDS-resident weights, block per batch row ----------
__global__ __launch_bounds__(128) void k_eta_all(
    const float* __restrict__ lstm_out, const float* __restrict__ mue_W,
    const float* __restrict__ mue_b, const float* __restrict__ lse_W,
    const float* __restrict__ lse_b, float* __restrict__ etas,
    double* __restrict__ acc, uint32_t ka, uint32_t kb) {
  __shared__ float wmu[KK * 306];   // 15300
  __shared__ float wls[KK * 306];   // 15300
  __shared__ float z[HE_ + KK];
  __shared__ float mu_s[KK], ls_s[KK];
  int b = blockIdx.x, tid = threadIdx.x;
  for (int i = tid; i < KK * 306; i += 128) { wmu[i] = mue_W[i]; wls[i] = lse_W[i]; }
  float klsum = 0.f;
  if (tid < KK) z[HE_ + tid] = 0.f;
  __syncthreads();
  for (int t = 0; t < TT; t++) {
    for (int i = tid; i < HE_; i += 128) z[i] = lstm_out[((size_t)t * BB + b) * HE_ + i];
    __syncthreads();
    if (tid < 100) {
      int j = tid % KK; bool isMu = tid < KK;
      const float* w = (isMu ? wmu : wls) + j * 306;
      float a = 0.f, a2 = 0.f;
      for (int i = 0; i < HE_ + KK; i += 2) {
        a = fmaf(z[i], w[i], a);
        a2 = fmaf(z[i + 1], w[i + 1], a2);
      }
      a += a2 + (isMu ? mue_b : lse_b)[j];
      if (isMu) mu_s[j] = a; else ls_s[j] = a;
    }
    __syncthreads();
    if (tid < KK) {
      float mu = mu_s[tid], ls = ls_s[tid];
      float eps = jax_normal_f(ka, kb, (uint32_t)((t * BB + b) * KK + tid));
      float eta = mu + eps * expf(0.5f * ls);
      float qls = fminf(fmaxf(ls, -100.f), 100.f);
      float pmu = z[HE_ + tid];
      float pls = (t == 0) ? 0.f : LOG_DELTA;
      float denom = (t == 0) ? DENOM0 : DENOM1;
      float d = mu - pmu;
      klsum += (expf(qls) + d * d) / denom - 1.0f + pls - qls;
      etas[((size_t)t * BB + b) * KK + tid] = eta;
      z[HE_ + tid] = eta;
    }
    __syncthreads();
  }
  if (tid < 64) {
    #pragma unroll
    for (int off = 32; off; off >>= 1) klsum += __shfl_down(klsum, off, 64);
    if (tid == 0) atomicAdd(&acc[3], (double)klsum);
  }
}

// ---------------- h1 tail: h1 = relu(bows_part + etas @ W1_tail^T) -> bf16 ----------------
__global__ __launch_bounds__(256) void k_h1(
    const float* __restrict__ etas, const short* __restrict__ tail_bf,
    const float* __restrict__ bows_part, short* __restrict__ h1_bf) {
  __shared__ float el[8][KK];
  int m0 = blockIdx.x * 8, tid = threadIdx.x;
  for (int idx = tid; idx < 8 * KK; idx += 256) {
    int mm = idx / KK, kk = idx % KK;
    el[mm][kk] = etas[(size_t)(m0 + mm) * KK + kk];
  }
  __syncthreads();
  for (int j = tid; j < HT_; j += 256) {
    const uint32_t* w = (const uint32_t*)(tail_bf + (size_t)j * KK);
    float wv[KK];
    #pragma unroll
    for (int k = 0; k < KK / 2; k++) {
      uint32_t u = w[k];
      wv[2 * k] = bf2f((short)u); wv[2 * k + 1] = bf2f((short)(u >> 16));
    }
    #pragma unroll
    for (int mm = 0; mm < 8; mm++) {
      int m = m0 + mm, b = m & (BB - 1);
      float a = bows_part[(size_t)b * HT_ + j];
      #pragma unroll
      for (int k = 0; k < KK; k++) a = fmaf(el[mm][k], wv[k], a);
      h1_bf[(size_t)m * HT_ + j] = f2bf(fmaxf(a, 0.f));
    }
  }
}

// ---------------- theta sampling head (mu/ls precomputed by GEMM) ----------------
__global__ __launch_bounds__(64) void k_theta2(
    const float* __restrict__ mu_ls, const float* __restrict__ etas,
    short* __restrict__ theta_bf, double* __restrict__ acc, uint32_t ka, uint32_t kb) {
  int m = blockIdx.x, tid = threadIdx.x;
  float kl = 0.f, zv = -INFINITY;
  if (tid < KK) {
    float mu = mu_ls[(size_t)m * 100 + tid];
    float ls = mu_ls[(size_t)m * 100 + KK + tid];
    float eps = jax_normal_f(ka, kb, (uint32_t)(m * KK + tid));
    zv = mu + eps * expf(0.5f * ls);
    float qls = fminf(fmaxf(ls, -100.f), 100.f);
    float e = etas[(size_t)m * KK + tid];
    float d = mu - e;
    kl = (expf(qls) + d * d) / DENOM0 - 1.0f - qls;
  }
  float mx = zv;
  #pragma unroll
  for (int off = 32; off; off >>= 1) mx = fmaxf(mx, __shfl_xor(mx, off, 64));
  float ev = (tid < KK) ? expf(zv - mx) : 0.f;
  float sum = ev;
  #pragma unroll
  for (int off = 32; off; off >>= 1) sum += __shfl_xor(sum, off, 64);
  if (tid < KK) theta_bf[(size_t)m * 56 + tid] = f2bf(ev / sum);
  #pragma unroll
  for (int off = 32; off; off >>= 1) kl += __shfl_down(kl, off, 64);
  if (tid == 0) atomicAdd(&acc[1], (double)kl);
}

__global__ void k_final(const double* __restrict__ acc, float* __restrict__ out) {
  if (threadIdx.x == 0 && blockIdx.x == 0) {
    out[0] = (float)(acc[0] * (10.0 / (double)BB));
    out[1] = (float)(acc[1] * (0.5 / ((double)TT * (double)BB)));
    out[2] = (float)(acc[2] * (0.5 / ((double)TT * (double)KK)));
    out[3] = (float)(acc[3] * (0.5 / (double)BB));
    out[4] = (float)(acc[4] * (-0.01));
  }
}

// ---------------- host ----------------
extern "C" void kernel_launch(void* const* d_in, const int* in_sizes, int n_in,
                              void* d_out, int out_size, void* d_ws, size_t ws_size,
                              hipStream_t stream) {
  const float* normalized_bows = (const float*)d_in[0];
  const float* bow_t  = (const float*)d_in[1];
  const float* adj    = (const float*)d_in[2];
  const float* mu_q   = (const float*)d_in[3];
  const float* ls_q   = (const float*)d_in[4];
  const float* rho_W  = (const float*)d_in[5];
  const float* rho_b  = (const float*)d_in[6];
  const float* qt_W1  = (const float*)d_in[7];
  const float* qt_b1  = (const float*)d_in[8];
  const float* qt_W2  = (const float*)d_in[9];
  const float* qt_b2  = (const float*)d_in[10];
  const float* mut_W  = (const float*)d_in[11];
  const float* mut_b  = (const float*)d_in[12];
  const float* lst_W  = (const float*)d_in[13];
  const float* lst_b  = (const float*)d_in[14];
  const float* qe_W   = (const float*)d_in[15];
  const float* qe_b   = (const float*)d_in[16];
  const float* Wih    = (const float*)d_in[17];
  const float* Whh    = (const float*)d_in[18];
  const float* bih    = (const float*)d_in[19];
  const float* bhh    = (const float*)d_in[20];
  const float* mue_W  = (const float*)d_in[21];
  const float* mue_b  = (const float*)d_in[22];
  const float* lse_W  = (const float*)d_in[23];
  const float* lse_b  = (const float*)d_in[24];
  float* out = (float*)d_out;

  // -------- workspace (floats; lifetime-overlapped; ~54 MB total) --------
  double* acc = (double*)d_ws;
  float* p          = (float*)d_ws + 16;
  float* betaT_f    = p;               p += 1500000;   // betaT  bf16 [5000][600]
  float* beta_bf_f  = p;               p += 1500000;   // beta   bf16 [600][5000]
  float* alphbf_f   = p;               p += 90000;     // alphas bf16 [600][300]
  float* rhoWbf_f   = p;               p += 750000;    // rho_W  bf16 [5000][300]
  float* arenaA     = p;               p += 3145728;   // logits f32 -> xg f32
  float* qeWbf_f    = p;               p += 640000;    // qe_W bf16
  float* Wihbf_f    = p;               p += 131072;    // Wih bf16
  float* arenaB     = p;               p += 2320000;   // qtW1_bf(2.0M)+qtW2_bf(0.32M); h1_bf overlays
  float* tailbf_f   = p;               p += 20000;     // qt_W1 tail bf16 [800][50]
  float* poolC      = p;               p += 2621440;   // inp|whhT|lstm_out -> h2 overlays
  float* sumbias    = p;               p += 1024;
  float* etas       = p;               p += 153600;
  float* bows_part  = p;               p += 204800;
  float* thbf_f     = p;               p += 86016;     // theta bf16 [3072][56]
  float* headWbf_f  = p;               p += 40000;     // [100][800] bf16
  float* head_b     = p;               p += 104;
  float* mu_ls      = p;               p += 307200;    // [3072][100] f32

  short* betaT    = (short*)betaT_f;
  short* beta_bf  = (short*)beta_bf_f;
  short* alph_bf  = (short*)alphbf_f;
  short* rhoW_bf  = (short*)rhoWbf_f;
  float* logits   = arenaA;
  float* xg       = arenaA;
  short* qeW_bf   = (short*)qeWbf_f;
  short* Wih_bf   = (short*)Wihbf_f;
  short* qtW1_bf  = (short*)arenaB;
  short* qtW2_bf  = (short*)(arenaB + 2000000);
  short* h1_bf    = (short*)arenaB;            // after qtW1 GEMM done
  short* tail_bf  = (short*)tailbf_f;
  float* inp      = poolC;
  float* whhT     = poolC + 786432;            // 262144 floats [256][1024]
  float* lstm_out = poolC + 786432 + 1048576;
  float* h2       = poolC;                     // after lstm/eta done
  short* theta_bf = (short*)thbf_f;
  short* headW_bf = (short*)headWbf_f;

  // JAX keys: key(42) -> split(3)
  uint32_t e0a, e0b, e1a, e1b, e2a, e2b;
  threefry2x32(0u, 42u, 0u, 0u, e0a, e0b);
  threefry2x32(0u, 42u, 0u, 1u, e1a, e1b);
  threefry2x32(0u, 42u, 0u, 2u, e2a, e2b);

  (void)hipMemsetAsync(acc, 0, 5 * sizeof(double), stream);

  // all weight conversions / transposes / bias inits in one kernel
  k_prep<<<8192, 256, 0, stream>>>(qe_W, Wih, qt_W2, qt_W1, rho_W, Whh, bih, bhh,
                                   qe_b, qt_b1, mut_W, mut_b, lst_W, lst_b,
                                   qeW_bf, Wih_bf, qtW2_bf, qtW1_bf, tail_bf, rhoW_bf,
                                   whhT, sumbias, inp, bows_part, headW_bf, head_b);

  // alphas (+ fused kld_alpha)
  k_alphas<<<704, 256, 0, stream>>>(mu_q, ls_q, alph_bf, acc, e0a, e0b);

  // beta = softmax(alphas @ rho_W^T + rho_b); bf16 row-major + transposed copy
  mfma_gemm<0, 0><<<dim3(40, 5), 256, 0, stream>>>(alph_bf, rhoW_bf, logits, rho_b,
      nullptr, nullptr, 600, VV, RHO_, RHO_, RHO_, VV, 0, 0, 0);
  k_softmax_bf<<<600, 256, 0, stream>>>(logits, beta_bf, VV);
  k_transpose_bf<<<dim3(157, 19), 256, 0, stream>>>(beta_bf, betaT, 600, VV);

  // cond = sum over (v,r) of betaT[v,r] * (adj @ beta^T)[v,r]; split-K=8
  mfma_gemm<2, 1><<<dim3(5, 40, 8), 256, 0, stream>>>(adj, beta_bf, nullptr, nullptr,
      betaT, acc + 4, VV, 600, VV, VV, VV, 0, 600, 640, 0);

  // inp = bow_t @ qe_W^T + qe_b (split-K atomic into bias-initialized inp)
  mfma_gemm<1, 1><<<dim3(2, 24, 8), 256, 0, stream>>>(bow_t, qeW_bf, inp, nullptr,
      nullptr, nullptr, 3072, HE_, VV, VV, VV, HE_, 0, 640, 0);
  // xg = inp @ Wih^T + (bih + bhh)
  mfma_gemm<0, 1><<<dim3(8, 24), 256, 0, stream>>>(inp, Wih_bf, xg, sumbias,
      nullptr, nullptr, 3072, 1024, HE_, HE_, HE_, 1024, 0, 0, 0);

  // fused scans
  k_lstm_all<<<64, 1024, 0, stream>>>(xg, whhT, lstm_out);
  k_eta_all<<<BB, 128, 0, stream>>>(lstm_out, mue_W, mue_b, lse_W, lse_b, etas, acc, e1a, e1b);

  // theta encoder
  mfma_gemm<1, 1><<<dim3(7, 2, 8), 256, 0, stream>>>(normalized_bows, qtW1_bf, bows_part,
      nullptr, nullptr, nullptr, BB, HT_, VV, VV, VV, HT_, 0, 640, 0);
  k_h1<<<384, 256, 0, stream>>>(etas, tail_bf, bows_part, h1_bf);
  mfma_gemm<0, 0><<<dim3(7, 24), 256, 0, stream>>>(h1_bf, qtW2_bf, h2, qt_b2,
      nullptr, nullptr, 3072, HT_, HT_, HT_, HT_, HT_, 0, 0, 1);
  // mu/ls head as one GEMM: [3072,100] = h2[3072,800] @ headW^T + head_b
  mfma_gemm<0, 1><<<dim3(1, 24), 256, 0, stream>>>(h2, headW_bf, mu_ls, head_b,
      nullptr, nullptr, 3072, 100, HT_, HT_, HT_, 100, 0, 0, 0);
  k_theta2<<<3072, 64, 0, stream>>>(mu_ls, etas, theta_bf, acc, e2a, e2b);

  // decode + nll
  k_decode64<<<dim3(79, 4, 12), 256, 0, stream>>>(theta_bf, betaT, bow_t, acc);

  k_final<<<1, 64, 0, stream>>>(acc, out);
}